// Round 1
// baseline (2849.122 us; speedup 1.0000x reference)
//
#include <hip/hip_runtime.h>
#include <hip/hip_bf16.h>

// Problem constants
constexpr int BATCH  = 4;
constexpr int CH     = 256;   // channels
constexpr int NPIX   = 4096;  // H*W = 64*64
constexpr int NGROUP = 32;
constexpr int CPG    = CH / NGROUP; // 8
constexpr int JS     = 8;     // j-slices for softmax stats
constexpr float ATTN_SCALE = 0.0625f; // C^-0.5 = 1/16
constexpr float GN_EPS = 1e-6f;

// ---------------------------------------------------------------------------
// K1: GroupNorm.  One block per (batch, group). 8 ch * 4096 = 32768 elements.
// ---------------------------------------------------------------------------
__global__ __launch_bounds__(256) void gn_kernel(
    const float* __restrict__ x, const float* __restrict__ gs,
    const float* __restrict__ gb, float* __restrict__ hn)
{
    const int b = blockIdx.x >> 5;
    const int g = blockIdx.x & 31;
    const long long base = ((long long)b * CH + (long long)g * CPG) * NPIX;
    const float4* xp = (const float4*)(x + base);
    constexpr int NV = CPG * NPIX / 4; // 8192 float4

    float s = 0.f, s2 = 0.f;
    for (int i = threadIdx.x; i < NV; i += 256) {
        float4 v = xp[i];
        s  += v.x + v.y + v.z + v.w;
        s2 += v.x*v.x + v.y*v.y + v.z*v.z + v.w*v.w;
    }
#pragma unroll
    for (int off = 32; off > 0; off >>= 1) {
        s  += __shfl_down(s,  off, 64);
        s2 += __shfl_down(s2, off, 64);
    }
    __shared__ float rs[4], rs2[4];
    __shared__ float smean, srstd;
    const int wid = threadIdx.x >> 6, lane = threadIdx.x & 63;
    if (lane == 0) { rs[wid] = s; rs2[wid] = s2; }
    __syncthreads();
    if (threadIdx.x == 0) {
        float ts  = rs[0] + rs[1] + rs[2] + rs[3];
        float ts2 = rs2[0] + rs2[1] + rs2[2] + rs2[3];
        float inv = 1.0f / (float)(CPG * NPIX);
        float mean = ts * inv;
        float var  = ts2 * inv - mean * mean;
        smean = mean;
        srstd = rsqrtf(var + GN_EPS);
    }
    __syncthreads();
    const float mean = smean, rstd = srstd;
    float4* hp = (float4*)(hn + base);
    for (int i = threadIdx.x; i < NV; i += 256) {
        int cc = i >> 10;              // 1024 float4 per channel
        int c  = g * CPG + cc;
        float sc = gs[c] * rstd;
        float bi = gb[c] - mean * sc;
        float4 v = xp[i];
        float4 o;
        o.x = v.x * sc + bi; o.y = v.y * sc + bi;
        o.z = v.z * sc + bi; o.w = v.w * sc + bi;
        hp[i] = o;
    }
}

// ---------------------------------------------------------------------------
// Templated fp32 GEMM: Out[m][n] = scale * sum_k A[m,k]*B[k,n] (+bias +resid)
//   A_TRANS  : global A is [m][k] (k contiguous) -> transpose-staged into LDS
//              else A is [k][m] (m contiguous)   -> natural staging
//   B always  [k][n] (n contiguous), natural staging
//   B_EXP    : staged B element gets exp(v - m[col]) * rl[col]  (softmax fused)
// Tile 128x128, BK=16, 256 threads, 8x8 micro-tile.
// ---------------------------------------------------------------------------
constexpr int BM = 128, BN = 128, BK = 16, LDST = 132;

template<bool A_TRANS, bool B_EXP, bool ADD_BIAS, bool ADD_RESID>
__global__ __launch_bounds__(256, 2) void gemm_k(
    const float* __restrict__ Ag, int lda, long long aBatch,
    const float* __restrict__ Bg, int ldb, long long bBatch,
    float* __restrict__ Og, int ldo, long long oBatch,
    const float* __restrict__ bias,
    const float* __restrict__ resid, long long rBatch,
    const float* __restrict__ mvec, const float* __restrict__ rlvec, int b0,
    int Kdim, float scale)
{
    __shared__ float As[BK][LDST];
    __shared__ float Bs[BK][LDST];
    __shared__ float smv[BN], srl[BN];

    const int tid = threadIdx.x;
    const int tx = tid & 15, ty = tid >> 4;
    const int m0 = blockIdx.y * BM, n0 = blockIdx.x * BN;
    const int z  = blockIdx.z;
    const float* Ab = Ag + (long long)z * aBatch;
    const float* Bb = Bg + (long long)z * bBatch;

    if constexpr (B_EXP) {
        if (tid < BN) {
            const int b = b0 + z;
            smv[tid] = mvec[(long long)b * NPIX + n0 + tid];
            srl[tid] = rlvec[(long long)b * NPIX + n0 + tid];
        }
        __syncthreads();
    }

    float acc[8][8];
#pragma unroll
    for (int i = 0; i < 8; ++i)
#pragma unroll
        for (int j = 0; j < 8; ++j) acc[i][j] = 0.f;

    for (int k0 = 0; k0 < Kdim; k0 += BK) {
        // ---- stage A ----
        if constexpr (A_TRANS) {
#pragma unroll
            for (int it = 0; it < 2; ++it) {
                int f  = tid + it * 256;          // 512 float4 total
                int mr = f >> 2;
                int k4 = (f & 3) << 2;
                float4 v = *(const float4*)&Ab[(long long)(m0 + mr) * lda + k0 + k4];
                As[k4 + 0][mr] = v.x; As[k4 + 1][mr] = v.y;
                As[k4 + 2][mr] = v.z; As[k4 + 3][mr] = v.w;
            }
        } else {
#pragma unroll
            for (int it = 0; it < 2; ++it) {
                int f  = tid + it * 256;
                int kr = f >> 5;
                int c4 = (f & 31) << 2;
                *(float4*)&As[kr][c4] =
                    *(const float4*)&Ab[(long long)(k0 + kr) * lda + m0 + c4];
            }
        }
        // ---- stage B ----
#pragma unroll
        for (int it = 0; it < 2; ++it) {
            int f  = tid + it * 256;
            int kr = f >> 5;
            int c4 = (f & 31) << 2;
            float4 v = *(const float4*)&Bb[(long long)(k0 + kr) * ldb + n0 + c4];
            if constexpr (B_EXP) {
                v.x = __expf(v.x - smv[c4 + 0]) * srl[c4 + 0];
                v.y = __expf(v.y - smv[c4 + 1]) * srl[c4 + 1];
                v.z = __expf(v.z - smv[c4 + 2]) * srl[c4 + 2];
                v.w = __expf(v.w - smv[c4 + 3]) * srl[c4 + 3];
            }
            *(float4*)&Bs[kr][c4] = v;
        }
        __syncthreads();
        // ---- compute ----
#pragma unroll
        for (int kk = 0; kk < BK; ++kk) {
            float a[8], bf[8];
            *(float4*)&a[0]  = *(const float4*)&As[kk][ty * 8];
            *(float4*)&a[4]  = *(const float4*)&As[kk][ty * 8 + 4];
            *(float4*)&bf[0] = *(const float4*)&Bs[kk][tx * 8];
            *(float4*)&bf[4] = *(const float4*)&Bs[kk][tx * 8 + 4];
#pragma unroll
            for (int i = 0; i < 8; ++i)
#pragma unroll
                for (int j = 0; j < 8; ++j)
                    acc[i][j] += a[i] * bf[j];
        }
        __syncthreads();
    }

    // ---- epilogue ----
#pragma unroll
    for (int i = 0; i < 8; ++i) {
        const long long m = m0 + ty * 8 + i;
        float bi = 0.f;
        if constexpr (ADD_BIAS) bi = bias[m];
#pragma unroll
        for (int jv = 0; jv < 8; jv += 4) {
            const long long n = n0 + tx * 8 + jv;
            float4 o;
            o.x = acc[i][jv + 0] * scale + bi;
            o.y = acc[i][jv + 1] * scale + bi;
            o.z = acc[i][jv + 2] * scale + bi;
            o.w = acc[i][jv + 3] * scale + bi;
            if constexpr (ADD_RESID) {
                float4 r = *(const float4*)&resid[(long long)z * rBatch + m * ldo + n];
                o.x += r.x; o.y += r.y; o.z += r.z; o.w += r.w;
            }
            *(float4*)&Og[(long long)z * oBatch + m * ldo + n] = o;
        }
    }
}

// ---------------------------------------------------------------------------
// Softmax column stats over St[b][j][i] (softmax along j for fixed column i).
// Pass 1 (sliced): per-slice max + sum(exp).  Pass 2: merge slices, store 1/l.
// ---------------------------------------------------------------------------
__global__ __launch_bounds__(256) void stats_partial(
    const float* __restrict__ StBase, long long stStride, int b0,
    float* __restrict__ pm, float* __restrict__ pl)
{
    const int z = blockIdx.z;
    const int b = b0 + z;
    const float* St = StBase + (long long)z * stStride;
    const int i  = blockIdx.x * 256 + threadIdx.x;
    const int s  = blockIdx.y;
    const int j0 = s * (NPIX / JS);
    const float* p = St + (long long)j0 * NPIX + i;

    float m0 = -3.4e38f, m1 = m0, m2 = m0, m3 = m0;
    for (int j = 0; j < NPIX / JS; j += 4) {
        m0 = fmaxf(m0, p[(long long)(j + 0) * NPIX]);
        m1 = fmaxf(m1, p[(long long)(j + 1) * NPIX]);
        m2 = fmaxf(m2, p[(long long)(j + 2) * NPIX]);
        m3 = fmaxf(m3, p[(long long)(j + 3) * NPIX]);
    }
    const float m = fmaxf(fmaxf(m0, m1), fmaxf(m2, m3));
    float l0 = 0.f, l1 = 0.f, l2 = 0.f, l3 = 0.f;
    for (int j = 0; j < NPIX / JS; j += 4) {
        l0 += __expf(p[(long long)(j + 0) * NPIX] - m);
        l1 += __expf(p[(long long)(j + 1) * NPIX] - m);
        l2 += __expf(p[(long long)(j + 2) * NPIX] - m);
        l3 += __expf(p[(long long)(j + 3) * NPIX] - m);
    }
    pm[((long long)s * BATCH + b) * NPIX + i] = m;
    pl[((long long)s * BATCH + b) * NPIX + i] = l0 + l1 + l2 + l3;
}

__global__ __launch_bounds__(256) void stats_merge(
    const float* __restrict__ pm, const float* __restrict__ pl,
    float* __restrict__ mOut, float* __restrict__ rlOut, int b0)
{
    const int b = b0 + blockIdx.y;
    const int i = blockIdx.x * 256 + threadIdx.x;
    float m = -3.4e38f;
#pragma unroll
    for (int s = 0; s < JS; ++s)
        m = fmaxf(m, pm[((long long)s * BATCH + b) * NPIX + i]);
    float l = 0.f;
#pragma unroll
    for (int s = 0; s < JS; ++s)
        l += pl[((long long)s * BATCH + b) * NPIX + i] *
             __expf(pm[((long long)s * BATCH + b) * NPIX + i] - m);
    mOut[(long long)b * NPIX + i]  = m;
    rlOut[(long long)b * NPIX + i] = 1.0f / l;
}

// ---------------------------------------------------------------------------
// Host launcher
// ---------------------------------------------------------------------------
extern "C" void kernel_launch(void* const* d_in, const int* in_sizes, int n_in,
                              void* d_out, int out_size, void* d_ws, size_t ws_size,
                              hipStream_t stream)
{
    const float* x  = (const float*)d_in[0];
    const float* gs = (const float*)d_in[1];
    const float* gb = (const float*)d_in[2];
    const float* qw = (const float*)d_in[3];
    const float* qb = (const float*)d_in[4];
    const float* kw = (const float*)d_in[5];
    const float* kb = (const float*)d_in[6];
    const float* vw = (const float*)d_in[7];
    const float* vb = (const float*)d_in[8];
    const float* pw = (const float*)d_in[9];
    const float* pb = (const float*)d_in[10];
    float* out = (float*)d_out;

    const long long CN = (long long)CH * NPIX;          // 1M floats
    float* ws    = (float*)d_ws;
    float* hn    = ws;
    float* qbuf  = hn   + CN * BATCH;
    float* kbuf  = qbuf + CN * BATCH;
    float* vbuf  = kbuf + CN * BATCH;
    float* ao    = vbuf + CN * BATCH;
    float* mbuf  = ao   + CN * BATCH;
    float* rlbuf = mbuf + (long long)BATCH * NPIX;
    float* pmb   = rlbuf + (long long)BATCH * NPIX;
    float* plb   = pmb  + (long long)JS * BATCH * NPIX;
    float* St    = plb  + (long long)JS * BATCH * NPIX;

    const size_t headFloats = (size_t)(St - ws);
    const size_t needAll = (headFloats + (size_t)BATCH * NPIX * NPIX) * sizeof(float);
    const bool batched = ws_size >= needAll;

    // K1: GroupNorm
    gn_kernel<<<BATCH * NGROUP, 256, 0, stream>>>(x, gs, gb, hn);

    // K2: q,k,v = W @ hn + b   (3 launches, batched over z)
    {
        dim3 g(NPIX / BN, CH / BM, BATCH);
        gemm_k<true, false, true, false><<<g, 256, 0, stream>>>(
            qw, CH, 0, hn, NPIX, CN, qbuf, NPIX, CN,
            qb, (const float*)nullptr, 0,
            (const float*)nullptr, (const float*)nullptr, 0, CH, 1.0f);
        gemm_k<true, false, true, false><<<g, 256, 0, stream>>>(
            kw, CH, 0, hn, NPIX, CN, kbuf, NPIX, CN,
            kb, (const float*)nullptr, 0,
            (const float*)nullptr, (const float*)nullptr, 0, CH, 1.0f);
        gemm_k<true, false, true, false><<<g, 256, 0, stream>>>(
            vw, CH, 0, hn, NPIX, CN, vbuf, NPIX, CN,
            vb, (const float*)nullptr, 0,
            (const float*)nullptr, (const float*)nullptr, 0, CH, 1.0f);
    }

    if (batched) {
        const long long SB = (long long)NPIX * NPIX;
        // K3: St[b][j][i] = scale * sum_c k[c][j] q[c][i]
        dim3 gS(NPIX / BN, NPIX / BM, BATCH);
        gemm_k<false, false, false, false><<<gS, 256, 0, stream>>>(
            kbuf, NPIX, CN, qbuf, NPIX, CN, St, NPIX, SB,
            (const float*)nullptr, (const float*)nullptr, 0,
            (const float*)nullptr, (const float*)nullptr, 0, CH, ATTN_SCALE);
        // K4: column softmax stats
        stats_partial<<<dim3(NPIX / 256, JS, BATCH), 256, 0, stream>>>(St, SB, 0, pmb, plb);
        stats_merge<<<dim3(NPIX / 256, BATCH), 256, 0, stream>>>(pmb, plb, mbuf, rlbuf, 0);
        // K5: ao[b][c][i] = sum_j v[c][j] * exp(St[j][i]-m_i)*rl_i
        dim3 gP(NPIX / BN, CH / BM, BATCH);
        gemm_k<true, true, false, false><<<gP, 256, 0, stream>>>(
            vbuf, NPIX, CN, St, NPIX, SB, ao, NPIX, CN,
            (const float*)nullptr, (const float*)nullptr, 0,
            mbuf, rlbuf, 0, NPIX, 1.0f);
    } else {
        // per-batch fallback (smaller workspace): reuse one N*N scores buffer
        for (int b = 0; b < BATCH; ++b) {
            dim3 gS(NPIX / BN, NPIX / BM, 1);
            gemm_k<false, false, false, false><<<gS, 256, 0, stream>>>(
                kbuf + (long long)b * CN, NPIX, 0, qbuf + (long long)b * CN, NPIX, 0,
                St, NPIX, 0,
                (const float*)nullptr, (const float*)nullptr, 0,
                (const float*)nullptr, (const float*)nullptr, 0, CH, ATTN_SCALE);
            stats_partial<<<dim3(NPIX / 256, JS, 1), 256, 0, stream>>>(St, 0, b, pmb, plb);
            stats_merge<<<dim3(NPIX / 256, 1), 256, 0, stream>>>(pmb, plb, mbuf, rlbuf, b);
            dim3 gP(NPIX / BN, CH / BM, 1);
            gemm_k<true, true, false, false><<<gP, 256, 0, stream>>>(
                vbuf + (long long)b * CN, NPIX, 0, St, NPIX, 0,
                ao + (long long)b * CN, NPIX, 0,
                (const float*)nullptr, (const float*)nullptr, 0,
                mbuf, rlbuf, b, NPIX, 1.0f);
        }
    }

    // K6: out = x + proj_w @ ao + proj_b
    {
        dim3 g(NPIX / BN, CH / BM, BATCH);
        gemm_k<true, false, true, true><<<g, 256, 0, stream>>>(
            pw, CH, 0, ao, NPIX, CN, out, NPIX, CN,
            pb, x, CN,
            (const float*)nullptr, (const float*)nullptr, 0, CH, 1.0f);
    }
}

// Round 2
// 763.022 us; speedup vs baseline: 3.7340x; 3.7340x over previous
//
#include <hip/hip_runtime.h>
#include <hip/hip_bf16.h>

typedef __attribute__((ext_vector_type(8))) short bf16x8;
typedef __attribute__((ext_vector_type(4))) float f32x4;
static_assert(sizeof(bf16x8) == 16, "");

constexpr int BATCH = 4, CH = 256, NPIX = 4096, NGROUP = 32, CPG = 8;
constexpr float ATTN_SCALE = 0.0625f;  // C^-0.5
constexpr float GN_EPS = 1e-6f;

__device__ inline short f2bf(float v) {
    union { __hip_bfloat16 b; short s; } u;
    u.b = __float2bfloat16(v);
    return u.s;
}
__device__ inline float bf2f(short s) {
    union { __hip_bfloat16 b; short sv; } u;
    u.sv = s;
    return __bfloat162float(u.b);
}

// ---------------------------------------------------------------------------
// K1: GroupNorm stats per (b, g): mean, rstd.
// ---------------------------------------------------------------------------
__global__ __launch_bounds__(256) void gn_stats(
    const float* __restrict__ x, float* __restrict__ meanb, float* __restrict__ rstdb)
{
    const int b = blockIdx.x >> 5;
    const int g = blockIdx.x & 31;
    const long long base = ((long long)b * CH + (long long)g * CPG) * NPIX;
    const float4* xp = (const float4*)(x + base);
    constexpr int NV = CPG * NPIX / 4;

    float s = 0.f, s2 = 0.f;
    for (int i = threadIdx.x; i < NV; i += 256) {
        float4 v = xp[i];
        s  += v.x + v.y + v.z + v.w;
        s2 += v.x * v.x + v.y * v.y + v.z * v.z + v.w * v.w;
    }
#pragma unroll
    for (int off = 32; off > 0; off >>= 1) {
        s  += __shfl_down(s,  off, 64);
        s2 += __shfl_down(s2, off, 64);
    }
    __shared__ float rs[4], rs2[4];
    const int wid = threadIdx.x >> 6, lane = threadIdx.x & 63;
    if (lane == 0) { rs[wid] = s; rs2[wid] = s2; }
    __syncthreads();
    if (threadIdx.x == 0) {
        float ts  = rs[0] + rs[1] + rs[2] + rs[3];
        float ts2 = rs2[0] + rs2[1] + rs2[2] + rs2[3];
        float inv = 1.0f / (float)(CPG * NPIX);
        float mu  = ts * inv;
        float var = ts2 * inv - mu * mu;
        meanb[blockIdx.x] = mu;
        rstdb[blockIdx.x] = rsqrtf(var + GN_EPS);
    }
}

// ---------------------------------------------------------------------------
// K2: transpose + normalize + convert: x[b][c][n] -> hnT_hi/lo[b][n][c] bf16.
// 64x64 tiles via LDS.
// ---------------------------------------------------------------------------
__global__ __launch_bounds__(256) void tn_cvt(
    const float* __restrict__ x, const float* __restrict__ gs, const float* __restrict__ gb,
    const float* __restrict__ meanb, const float* __restrict__ rstdb,
    __hip_bfloat16* __restrict__ th, __hip_bfloat16* __restrict__ tl)
{
    __shared__ float t[64][65];
    const int b = blockIdx.z, c0 = blockIdx.y * 64, n0 = blockIdx.x * 64;
    const int tid = threadIdx.x;
    const int rr_ = tid >> 2, q4 = (tid & 3) * 16;
    {
        const int c = c0 + rr_;
        const int g = c >> 3;
        const float mu = meanb[b * NGROUP + g], rs = rstdb[b * NGROUP + g];
        const float A = gs[c] * rs, Bc = gb[c] - mu * A;
        const float* xs = x + ((long long)b * CH + c) * NPIX + n0 + q4;
#pragma unroll
        for (int p = 0; p < 4; ++p) {
            float4 vv = *(const float4*)(xs + p * 4);
            t[rr_][q4 + p * 4 + 0] = vv.x * A + Bc;
            t[rr_][q4 + p * 4 + 1] = vv.y * A + Bc;
            t[rr_][q4 + p * 4 + 2] = vv.z * A + Bc;
            t[rr_][q4 + p * 4 + 3] = vv.w * A + Bc;
        }
    }
    __syncthreads();
    {
        const int n = n0 + rr_;
        const long long ob = ((long long)b * NPIX + n) * CH + c0 + q4;
        union { short s[16]; bf16x8 v[2]; } hs, ls;
#pragma unroll
        for (int p = 0; p < 16; ++p) {
            float v = t[q4 + p][rr_];
            short h = f2bf(v);
            hs.s[p] = h;
            ls.s[p] = f2bf(v - bf2f(h));
        }
        *(bf16x8*)(th + ob)      = hs.v[0];
        *(bf16x8*)(th + ob + 8)  = hs.v[1];
        *(bf16x8*)(tl + ob)      = ls.v[0];
        *(bf16x8*)(tl + ob + 8)  = ls.v[1];
    }
}

// ---------------------------------------------------------------------------
// K3: convert the four 256x256 weight matrices to bf16 hi/lo (packed).
// ---------------------------------------------------------------------------
__global__ __launch_bounds__(256) void wcvt(
    const float* __restrict__ qw, const float* __restrict__ kw,
    const float* __restrict__ vw, const float* __restrict__ pw,
    __hip_bfloat16* __restrict__ wh, __hip_bfloat16* __restrict__ wl)
{
    const int idx = (blockIdx.x * 256 + threadIdx.x) * 4;
    const int which = idx >> 16;
    const float* src = which == 0 ? qw : which == 1 ? kw : which == 2 ? vw : pw;
    float4 vv = *(const float4*)(src + (idx & 65535));
    float a[4] = {vv.x, vv.y, vv.z, vv.w};
#pragma unroll
    for (int e = 0; e < 4; ++e) {
        short h = f2bf(a[e]);
        ((short*)wh)[idx + e] = h;
        ((short*)wl)[idx + e] = f2bf(a[e] - bf2f(h));
    }
}

// ---------------------------------------------------------------------------
// MFMA GEMM.  Out[m][n] = sum_k A[m][k]*B[n][k]  (both operands K-contiguous)
// PAIR: 3-term split-bf16 (hi*hi + hi*lo + lo*hi).  AEXP: A staged from fp32
// S with fused exp(v-m)*rl, hi-only.  EPI: 0 fp32*scale, 1 bf16-pair(+bias),
// 2 fp32+bias+resid.  BIAS: 0 none, 1 per-row(m), 2 per-col(n).
// Tile 128x128, BK=32 bf16, 256 threads (4 waves, 2x2 of 64x64).
// ---------------------------------------------------------------------------
__device__ inline void ld_tile(const __hip_bfloat16* g, long long ld, long long row0,
                               int k0, bf16x8* r) {
#pragma unroll
    for (int i = 0; i < 2; ++i) {
        const int o = threadIdx.x * 16 + i * 4096;
        r[i] = *(const bf16x8*)((const char*)(g + (row0 + (o >> 6)) * ld + k0) + (o & 63));
    }
}
__device__ inline void st_tile(char* lds, const bf16x8* r) {
#pragma unroll
    for (int i = 0; i < 2; ++i) {
        const int o = threadIdx.x * 16 + i * 4096;
        *(bf16x8*)(lds + o) = r[i];
    }
}

template<bool PAIR, bool AEXP, int EPI, int BIAS>
__global__ __launch_bounds__(256, 2) void mgemm(
    const __hip_bfloat16* __restrict__ Ah, const __hip_bfloat16* __restrict__ Al,
    long long aB, int lda,
    const float* __restrict__ Af, long long afB,
    const __hip_bfloat16* __restrict__ Bh, const __hip_bfloat16* __restrict__ Bl,
    long long bB, int ldb,
    float* __restrict__ Of, __hip_bfloat16* __restrict__ Oh, __hip_bfloat16* __restrict__ Ol,
    long long oB, int ldo,
    const float* __restrict__ bias,
    const float* __restrict__ resid, long long rB,
    const float* __restrict__ mrow, const float* __restrict__ rlrow, int b0,
    int Kd, float scale)
{
    extern __shared__ char sm[];
    char* smAh = sm;                 // 2 x 8192
    char* smBh = sm + 16384;         // 2 x 8192
    char* smAl = sm + 32768;         // PAIR only
    char* smBl = sm + 49152;

    const int tid = threadIdx.x;
    // XCD-aware swizzle (grid x*y is always a multiple of 8 here)
    const int nx = gridDim.x;
    const int nwg = nx * gridDim.y;
    int id = blockIdx.y * nx + blockIdx.x;
    id = (id & 7) * (nwg >> 3) + (id >> 3);
    const int n0 = (id % nx) * 128;
    const int m0 = (id / nx) * 128;
    const int z = blockIdx.z;

    const __hip_bfloat16* pAh = Ah + (long long)z * aB;
    const __hip_bfloat16* pAl = Al + (long long)z * aB;
    const __hip_bfloat16* pBh = Bh + (long long)z * bB;
    const __hip_bfloat16* pBl = Bl + (long long)z * bB;
    const float* pAf = Af + (long long)z * afB;

    float mr = 0.f, rr = 0.f;
    if constexpr (AEXP) {
        const long long row = m0 + (tid >> 1);
        mr = mrow[(long long)(b0 + z) * NPIX + row];
        rr = rlrow[(long long)(b0 + z) * NPIX + row];
    }

    f32x4 acc[4][4];
#pragma unroll
    for (int i = 0; i < 4; ++i)
#pragma unroll
        for (int j = 0; j < 4; ++j) acc[i][j] = (f32x4){0.f, 0.f, 0.f, 0.f};

    const int nt = Kd >> 5;
    bf16x8 rAh[2], rAl[2], rBh[2], rBl[2];
    float4 rAf[4];

    const int lane = tid & 63, wid = tid >> 6;
    const int wr = (wid >> 1) * 64, wc = (wid & 1) * 64;
    const int fr = lane & 15, fh = (lane >> 4) * 16;  // frag row, k-half byte off

#define LOADT(t_)                                                                 \
    {                                                                             \
        const int k0 = (t_) << 5;                                                 \
        if constexpr (AEXP) {                                                     \
            const float* s_ = pAf + (long long)(m0 + (tid >> 1)) * lda + k0 +     \
                              (tid & 1) * 16;                                     \
            _Pragma("unroll") for (int p = 0; p < 4; ++p)                         \
                rAf[p] = *(const float4*)(s_ + p * 4);                            \
        } else {                                                                  \
            ld_tile(pAh, lda, m0, k0, rAh);                                       \
            if constexpr (PAIR) ld_tile(pAl, lda, m0, k0, rAl);                   \
        }                                                                         \
        ld_tile(pBh, ldb, n0, k0, rBh);                                           \
        if constexpr (PAIR) ld_tile(pBl, ldb, n0, k0, rBl);                       \
    }

#define WRITET(buf_)                                                              \
    {                                                                             \
        char* a_ = smAh + (buf_) * 8192;                                          \
        if constexpr (AEXP) {                                                     \
            union { short s[16]; bf16x8 v[2]; } u;                                \
            _Pragma("unroll") for (int p = 0; p < 4; ++p) {                       \
                float e0 = __expf(rAf[p].x - mr) * rr;                            \
                float e1 = __expf(rAf[p].y - mr) * rr;                            \
                float e2 = __expf(rAf[p].z - mr) * rr;                            \
                float e3 = __expf(rAf[p].w - mr) * rr;                            \
                u.s[p * 4 + 0] = f2bf(e0); u.s[p * 4 + 1] = f2bf(e1);             \
                u.s[p * 4 + 2] = f2bf(e2); u.s[p * 4 + 3] = f2bf(e3);             \
            }                                                                     \
            char* d_ = a_ + (tid >> 1) * 64 + (tid & 1) * 32;                     \
            *(bf16x8*)d_ = u.v[0];                                                \
            *(bf16x8*)(d_ + 16) = u.v[1];                                         \
        } else {                                                                  \
            st_tile(a_, rAh);                                                     \
            if constexpr (PAIR) st_tile(smAl + (buf_) * 8192, rAl);               \
        }                                                                         \
        st_tile(smBh + (buf_) * 8192, rBh);                                       \
        if constexpr (PAIR) st_tile(smBl + (buf_) * 8192, rBl);                   \
    }

#define COMPUTE(buf_)                                                             \
    {                                                                             \
        const char* a_ = smAh + (buf_) * 8192;                                    \
        const char* al_ = smAl + (buf_) * 8192;                                   \
        const char* bh_ = smBh + (buf_) * 8192;                                   \
        const char* bl_ = smBl + (buf_) * 8192;                                   \
        bf16x8 af[4], afl[4];                                                     \
        _Pragma("unroll") for (int fm = 0; fm < 4; ++fm) {                        \
            const int off = (wr + fm * 16 + fr) * 64 + fh;                        \
            af[fm] = *(const bf16x8*)(a_ + off);                                  \
            if constexpr (PAIR) afl[fm] = *(const bf16x8*)(al_ + off);            \
        }                                                                         \
        _Pragma("unroll") for (int fn = 0; fn < 4; ++fn) {                        \
            const int off = (wc + fn * 16 + fr) * 64 + fh;                        \
            bf16x8 bfh = *(const bf16x8*)(bh_ + off);                             \
            _Pragma("unroll") for (int fm = 0; fm < 4; ++fm)                      \
                acc[fm][fn] = __builtin_amdgcn_mfma_f32_16x16x32_bf16(            \
                    af[fm], bfh, acc[fm][fn], 0, 0, 0);                           \
            if constexpr (PAIR) {                                                 \
                bf16x8 bfl = *(const bf16x8*)(bl_ + off);                         \
                _Pragma("unroll") for (int fm = 0; fm < 4; ++fm) {                \
                    acc[fm][fn] = __builtin_amdgcn_mfma_f32_16x16x32_bf16(        \
                        af[fm], bfl, acc[fm][fn], 0, 0, 0);                       \
                    acc[fm][fn] = __builtin_amdgcn_mfma_f32_16x16x32_bf16(        \
                        afl[fm], bfh, acc[fm][fn], 0, 0, 0);                      \
                }                                                                 \
            }                                                                     \
        }                                                                         \
    }

    LOADT(0);
    WRITET(0);
    __syncthreads();
    for (int t = 0; t < nt; ++t) {
        if (t + 1 < nt) LOADT(t + 1);
        COMPUTE(t & 1);
        if (t + 1 < nt) WRITET((t + 1) & 1);
        __syncthreads();
    }
#undef LOADT
#undef WRITET
#undef COMPUTE

    // epilogue
#pragma unroll
    for (int fm = 0; fm < 4; ++fm) {
#pragma unroll
        for (int fn = 0; fn < 4; ++fn) {
#pragma unroll
            for (int j = 0; j < 4; ++j) {
                const long long gr = m0 + wr + fm * 16 + (lane >> 4) * 4 + j;
                const long long gc = n0 + wc + fn * 16 + (lane & 15);
                float v = acc[fm][fn][j];
                if constexpr (EPI == 0) {
                    Of[(long long)z * oB + gr * ldo + gc] = v * scale;
                } else if constexpr (EPI == 1) {
                    if constexpr (BIAS == 1) v += bias[gr];
                    if constexpr (BIAS == 2) v += bias[gc];
                    const long long o = (long long)z * oB + gr * ldo + gc;
                    short h = f2bf(v);
                    ((short*)Oh)[o] = h;
                    ((short*)Ol)[o] = f2bf(v - bf2f(h));
                } else {
                    const float rv = resid[(long long)z * rB + gr * ldo + gc];
                    Of[(long long)z * oB + gr * ldo + gc] = v + bias[gr] + rv;
                }
            }
        }
    }
}

// ---------------------------------------------------------------------------
// K5: row softmax stats over S[b][i][:]  (contiguous rows).
// ---------------------------------------------------------------------------
__global__ __launch_bounds__(256) void smax_rows(
    const float* __restrict__ S, long long sB,
    float* __restrict__ mrow, float* __restrict__ rlrow, int b0)
{
    const int z = blockIdx.y;
    const int i = blockIdx.x;
    const float* row = S + (long long)z * sB + (long long)i * NPIX;
    const int tid = threadIdx.x;
    float v[16];
#pragma unroll
    for (int p = 0; p < 4; ++p) {
        float4 q = *(const float4*)(row + tid * 4 + p * 1024);
        v[p * 4 + 0] = q.x; v[p * 4 + 1] = q.y;
        v[p * 4 + 2] = q.z; v[p * 4 + 3] = q.w;
    }
    float m = v[0];
#pragma unroll
    for (int e = 1; e < 16; ++e) m = fmaxf(m, v[e]);
#pragma unroll
    for (int off = 32; off > 0; off >>= 1) m = fmaxf(m, __shfl_xor(m, off, 64));
    __shared__ float wm[4], wl[4];
    const int wid = tid >> 6, lane = tid & 63;
    if (lane == 0) wm[wid] = m;
    __syncthreads();
    m = fmaxf(fmaxf(wm[0], wm[1]), fmaxf(wm[2], wm[3]));
    float l = 0.f;
#pragma unroll
    for (int e = 0; e < 16; ++e) l += __expf(v[e] - m);
#pragma unroll
    for (int off = 32; off > 0; off >>= 1) l += __shfl_xor(l, off, 64);
    if (lane == 0) wl[wid] = l;
    __syncthreads();
    if (tid == 0) {
        l = wl[0] + wl[1] + wl[2] + wl[3];
        mrow[(long long)(b0 + z) * NPIX + i]  = m;
        rlrow[(long long)(b0 + z) * NPIX + i] = 1.0f / l;
    }
}

// ---------------------------------------------------------------------------
// Host launcher
// ---------------------------------------------------------------------------
extern "C" void kernel_launch(void* const* d_in, const int* in_sizes, int n_in,
                              void* d_out, int out_size, void* d_ws, size_t ws_size,
                              hipStream_t stream)
{
    const float* x  = (const float*)d_in[0];
    const float* gs = (const float*)d_in[1];
    const float* gb = (const float*)d_in[2];
    const float* qw = (const float*)d_in[3];
    const float* qb = (const float*)d_in[4];
    const float* kw = (const float*)d_in[5];
    const float* kb = (const float*)d_in[6];
    const float* vw = (const float*)d_in[7];
    const float* vb = (const float*)d_in[8];
    const float* pw = (const float*)d_in[9];
    const float* pb = (const float*)d_in[10];
    float* out = (float*)d_out;

    char* w = (char*)d_ws;
    size_t used = 0;
    auto alloc = [&](size_t bytes) {
        char* p = w + used;
        used += (bytes + 255) & ~(size_t)255;
        return p;
    };
    const long long NC = (long long)NPIX * CH;      // 1M elems
    const long long SB = (long long)NPIX * NPIX;    // 16M elems

    __hip_bfloat16* hnT_h = (__hip_bfloat16*)alloc(BATCH * NC * 2);
    __hip_bfloat16* hnT_l = (__hip_bfloat16*)alloc(BATCH * NC * 2);
    __hip_bfloat16* qT_h  = (__hip_bfloat16*)alloc(BATCH * NC * 2);
    __hip_bfloat16* qT_l  = (__hip_bfloat16*)alloc(BATCH * NC * 2);
    __hip_bfloat16* kT_h  = (__hip_bfloat16*)alloc(BATCH * NC * 2);
    __hip_bfloat16* kT_l  = (__hip_bfloat16*)alloc(BATCH * NC * 2);
    __hip_bfloat16* v_h   = (__hip_bfloat16*)alloc(BATCH * NC * 2);
    __hip_bfloat16* v_l   = (__hip_bfloat16*)alloc(BATCH * NC * 2);
    __hip_bfloat16* aoT_h = (__hip_bfloat16*)alloc(BATCH * NC * 2);
    __hip_bfloat16* aoT_l = (__hip_bfloat16*)alloc(BATCH * NC * 2);
    __hip_bfloat16* w4h   = (__hip_bfloat16*)alloc(4 * 65536 * 2);
    __hip_bfloat16* w4l   = (__hip_bfloat16*)alloc(4 * 65536 * 2);
    float* meanb = (float*)alloc(BATCH * NGROUP * 4);
    float* rstdb = (float*)alloc(BATCH * NGROUP * 4);
    float* mrow  = (float*)alloc(BATCH * NPIX * 4);
    float* rlrow = (float*)alloc(BATCH * NPIX * 4);

    const bool batched = ws_size >= used + (size_t)BATCH * SB * 4;
    float* S = (float*)alloc((batched ? (size_t)BATCH : 1) * SB * 4);

    const __hip_bfloat16 *wq_h = w4h,          *wq_l = w4l;
    const __hip_bfloat16 *wk_h = w4h + 65536,  *wk_l = w4l + 65536;
    const __hip_bfloat16 *wv_h = w4h + 131072, *wv_l = w4l + 131072;
    const __hip_bfloat16 *wp_h = w4h + 196608, *wp_l = w4l + 196608;

    // K1 + K2 + K3
    gn_stats<<<BATCH * NGROUP, 256, 0, stream>>>(x, meanb, rstdb);
    tn_cvt<<<dim3(NPIX / 64, CH / 64, BATCH), 256, 0, stream>>>(
        x, gs, gb, meanb, rstdb, hnT_h, hnT_l);
    wcvt<<<256, 256, 0, stream>>>(qw, kw, vw, pw, w4h, w4l);

    const int SMP = 65536, SM1 = 32768;
    // qT[i][c], kT[i][c]  (M=NPIX, N=CH, K=CH; bias per col)
    mgemm<true, false, 1, 2><<<dim3(2, 32, BATCH), 256, SMP, stream>>>(
        hnT_h, hnT_l, NC, CH, nullptr, 0, wq_h, wq_l, 0, CH,
        nullptr, qT_h, qT_l, NC, CH, qb, nullptr, 0, nullptr, nullptr, 0, CH, 1.0f);
    mgemm<true, false, 1, 2><<<dim3(2, 32, BATCH), 256, SMP, stream>>>(
        hnT_h, hnT_l, NC, CH, nullptr, 0, wk_h, wk_l, 0, CH,
        nullptr, kT_h, kT_l, NC, CH, kb, nullptr, 0, nullptr, nullptr, 0, CH, 1.0f);
    // v[c][j]  (M=CH, N=NPIX, K=CH; bias per row)
    mgemm<true, false, 1, 1><<<dim3(32, 2, BATCH), 256, SMP, stream>>>(
        wv_h, wv_l, 0, CH, nullptr, 0, hnT_h, hnT_l, NC, CH,
        nullptr, v_h, v_l, NC, NPIX, vb, nullptr, 0, nullptr, nullptr, 0, CH, 1.0f);

    if (batched) {
        // S[i][j] fp32
        mgemm<true, false, 0, 0><<<dim3(32, 32, BATCH), 256, SMP, stream>>>(
            qT_h, qT_l, NC, CH, nullptr, 0, kT_h, kT_l, NC, CH,
            S, nullptr, nullptr, SB, NPIX, nullptr, nullptr, 0,
            nullptr, nullptr, 0, CH, ATTN_SCALE);
        smax_rows<<<dim3(NPIX, BATCH), 256, 0, stream>>>(S, SB, mrow, rlrow, 0);
        // aoT[i][c] = sum_j exp(S[i][j]-m)*rl * v[c][j]
        mgemm<false, true, 1, 0><<<dim3(2, 32, BATCH), 256, SM1, stream>>>(
            nullptr, nullptr, 0, NPIX, S, SB, v_h, nullptr, NC, NPIX,
            nullptr, aoT_h, aoT_l, NC, CH, nullptr, nullptr, 0,
            mrow, rlrow, 0, NPIX, 1.0f);
    } else {
        for (int b = 0; b < BATCH; ++b) {
            mgemm<true, false, 0, 0><<<dim3(32, 32, 1), 256, SMP, stream>>>(
                qT_h + b * NC, qT_l + b * NC, 0, CH, nullptr, 0,
                kT_h + b * NC, kT_l + b * NC, 0, CH,
                S, nullptr, nullptr, 0, NPIX, nullptr, nullptr, 0,
                nullptr, nullptr, 0, CH, ATTN_SCALE);
            smax_rows<<<dim3(NPIX, 1), 256, 0, stream>>>(S, 0, mrow, rlrow, b);
            mgemm<false, true, 1, 0><<<dim3(2, 32, 1), 256, SM1, stream>>>(
                nullptr, nullptr, 0, NPIX, S, 0, v_h + b * NC, nullptr, 0, NPIX,
                nullptr, aoT_h + b * NC, aoT_l + b * NC, 0, CH, nullptr, nullptr, 0,
                mrow, rlrow, b, NPIX, 1.0f);
        }
    }

    // out[c][n] = x + pb[c] + sum_k pw[c][k] * aoT[n][k]
    mgemm<true, false, 2, 1><<<dim3(32, 2, BATCH), 256, SMP, stream>>>(
        wp_h, wp_l, 0, CH, nullptr, 0, aoT_h, aoT_l, NC, CH,
        out, nullptr, nullptr, NC, NPIX, pb, x, NC,
        nullptr, nullptr, 0, CH, 1.0f);
}

// Round 3
// 516.313 us; speedup vs baseline: 5.5182x; 1.4778x over previous
//
#include <hip/hip_runtime.h>
#include <hip/hip_bf16.h>

typedef __attribute__((ext_vector_type(8))) short bf16x8;
typedef __attribute__((ext_vector_type(4))) float f32x4;
static_assert(sizeof(bf16x8) == 16, "");

constexpr int BATCH = 4, CH = 256, NPIX = 4096, NGROUP = 32, CPG = 8;
constexpr float ATTN_SCALE = 0.0625f;  // C^-0.5
constexpr float GN_EPS = 1e-6f;

__device__ inline short f2bf(float v) {
    union { __hip_bfloat16 b; short s; } u;
    u.b = __float2bfloat16(v);
    return u.s;
}
__device__ inline float bf2f(short s) {
    union { __hip_bfloat16 b; short sv; } u;
    u.sv = s;
    return __bfloat162float(u.b);
}

// ---- async global->LDS (16B per lane), with reg-staged fallback ----------
#if defined(__has_builtin)
#if __has_builtin(__builtin_amdgcn_global_load_lds)
#define HAVE_GLDS 1
#endif
#endif

typedef const __attribute__((address_space(1))) char* gas_t;
typedef __attribute__((address_space(3))) char* las_t;

__device__ inline void gload16(const void* g, char* l) {
#ifdef HAVE_GLDS
    __builtin_amdgcn_global_load_lds((gas_t)g, (las_t)l, 16, 0, 0);
#else
    *(bf16x8*)l = *(const bf16x8*)g;
#endif
}

// LDS bank swizzle: byte-col (16B granular) XOR'd by row bits -> 2-way max.
#define SWZ(r_, c_) ((c_) ^ ((((r_) >> 1) & 3) << 4))

// Stage one 128x32 bf16 tile (8 KB) into LDS, pre-swizzled source (rule #21).
__device__ inline void stage_tile(const __hip_bfloat16* __restrict__ g,
                                  long long ld, long long row0, int k0,
                                  char* lds) {
#pragma unroll
    for (int i = 0; i < 2; ++i) {
        const int o = (int)threadIdx.x * 16 + i * 4096;
        const int row = o >> 6, col = o & 63;
        gload16((const char*)(g + (row0 + row) * ld + k0) + SWZ(row, col), lds + o);
    }
}

// ---------------------------------------------------------------------------
// K1: GroupNorm stats per (b, g): mean, rstd.
// ---------------------------------------------------------------------------
__global__ __launch_bounds__(256) void gn_stats(
    const float* __restrict__ x, float* __restrict__ meanb, float* __restrict__ rstdb)
{
    const int b = blockIdx.x >> 5;
    const int g = blockIdx.x & 31;
    const long long base = ((long long)b * CH + (long long)g * CPG) * NPIX;
    const float4* xp = (const float4*)(x + base);
    constexpr int NV = CPG * NPIX / 4;

    float s = 0.f, s2 = 0.f;
    for (int i = threadIdx.x; i < NV; i += 256) {
        float4 v = xp[i];
        s  += v.x + v.y + v.z + v.w;
        s2 += v.x * v.x + v.y * v.y + v.z * v.z + v.w * v.w;
    }
#pragma unroll
    for (int off = 32; off > 0; off >>= 1) {
        s  += __shfl_down(s,  off, 64);
        s2 += __shfl_down(s2, off, 64);
    }
    __shared__ float rs[4], rs2[4];
    const int wid = threadIdx.x >> 6, lane = threadIdx.x & 63;
    if (lane == 0) { rs[wid] = s; rs2[wid] = s2; }
    __syncthreads();
    if (threadIdx.x == 0) {
        float ts  = rs[0] + rs[1] + rs[2] + rs[3];
        float ts2 = rs2[0] + rs2[1] + rs2[2] + rs2[3];
        float inv = 1.0f / (float)(CPG * NPIX);
        float mu  = ts * inv;
        float var = ts2 * inv - mu * mu;
        meanb[blockIdx.x] = mu;
        rstdb[blockIdx.x] = rsqrtf(var + GN_EPS);
    }
}

// ---------------------------------------------------------------------------
// K2: transpose + normalize + convert: x[b][c][n] -> hnT_hi/lo[b][n][c] bf16.
// ---------------------------------------------------------------------------
__global__ __launch_bounds__(256) void tn_cvt(
    const float* __restrict__ x, const float* __restrict__ gs, const float* __restrict__ gb,
    const float* __restrict__ meanb, const float* __restrict__ rstdb,
    __hip_bfloat16* __restrict__ th, __hip_bfloat16* __restrict__ tl)
{
    __shared__ float t[64][65];
    const int b = blockIdx.z, c0 = blockIdx.y * 64, n0 = blockIdx.x * 64;
    const int tid = threadIdx.x;
    const int rr_ = tid >> 2, q4 = (tid & 3) * 16;
    {
        const int c = c0 + rr_;
        const int g = c >> 3;
        const float mu = meanb[b * NGROUP + g], rs = rstdb[b * NGROUP + g];
        const float A = gs[c] * rs, Bc = gb[c] - mu * A;
        const float* xs = x + ((long long)b * CH + c) * NPIX + n0 + q4;
#pragma unroll
        for (int p = 0; p < 4; ++p) {
            float4 vv = *(const float4*)(xs + p * 4);
            t[rr_][q4 + p * 4 + 0] = vv.x * A + Bc;
            t[rr_][q4 + p * 4 + 1] = vv.y * A + Bc;
            t[rr_][q4 + p * 4 + 2] = vv.z * A + Bc;
            t[rr_][q4 + p * 4 + 3] = vv.w * A + Bc;
        }
    }
    __syncthreads();
    {
        const int n = n0 + rr_;
        const long long ob = ((long long)b * NPIX + n) * CH + c0 + q4;
        union { short s[16]; bf16x8 v[2]; } hs, ls;
#pragma unroll
        for (int p = 0; p < 16; ++p) {
            float v = t[q4 + p][rr_];
            short h = f2bf(v);
            hs.s[p] = h;
            ls.s[p] = f2bf(v - bf2f(h));
        }
        *(bf16x8*)(th + ob)      = hs.v[0];
        *(bf16x8*)(th + ob + 8)  = hs.v[1];
        *(bf16x8*)(tl + ob)      = ls.v[0];
        *(bf16x8*)(tl + ob + 8)  = ls.v[1];
    }
}

// ---------------------------------------------------------------------------
// K3: convert the four 256x256 weight matrices to bf16 hi/lo (packed).
// ---------------------------------------------------------------------------
__global__ __launch_bounds__(256) void wcvt(
    const float* __restrict__ qw, const float* __restrict__ kw,
    const float* __restrict__ vw, const float* __restrict__ pw,
    __hip_bfloat16* __restrict__ wh, __hip_bfloat16* __restrict__ wl)
{
    const int idx = (blockIdx.x * 256 + threadIdx.x) * 4;
    const int which = idx >> 16;
    const float* src = which == 0 ? qw : which == 1 ? kw : which == 2 ? vw : pw;
    float4 vv = *(const float4*)(src + (idx & 65535));
    float a[4] = {vv.x, vv.y, vv.z, vv.w};
#pragma unroll
    for (int e = 0; e < 4; ++e) {
        short h = f2bf(a[e]);
        ((short*)wh)[idx + e] = h;
        ((short*)wl)[idx + e] = f2bf(a[e] - bf2f(h));
    }
}

// ---------------------------------------------------------------------------
// MFMA GEMM, global_load_lds staged, 2-phase schedule, swizzled LDS.
// Out[m][n] = sum_k A[m][k]*B[n][k] (both K-contiguous).
// PAIR: split-bf16 3-pass. AEXP: A from fp32 S with fused exp(v-m)*rl (hi).
// EPI: 0 fp32*scale, 1 bf16 hi[/lo]+bias, 2 fp32+bias+resid, 3 fp32 raw.
// BIAS: 0/1 row/2 col. STATS: fused per-64col softmax partials. QK: dual-B.
// z mapping: bb = bbase + (z & zmask); sel = z >> zshift; kbeg = sel*kstep.
// ---------------------------------------------------------------------------
constexpr int AHOFF = 0, ALOFF = 16384;

#define STAGE_AB(buf_, k0_) {                                                  \
    if constexpr (!AEXP) {                                                     \
        stage_tile(pAh, lda, m0, (k0_), sm + AHOFF + (buf_) * 8192);           \
        if constexpr (PAIR)                                                    \
            stage_tile(pAl, lda, m0, (k0_), sm + ALOFF + (buf_) * 8192);       \
    }                                                                          \
    stage_tile(pBh, ldb, n0, (k0_), sm + BHOFF + (buf_) * 8192);               \
    if constexpr (PAIR)                                                        \
        stage_tile(pBl, ldb, n0, (k0_), sm + BLOFF + (buf_) * 8192);           \
}

#define ALOADM(k0_) {                                                          \
    const float* s_ = pAf + (long long)(m0 + (tid >> 1)) * lda + (k0_) +       \
                      (tid & 1) * 16;                                          \
    _Pragma("unroll") for (int p = 0; p < 4; ++p)                              \
        rAf[p] = *(const float4*)(s_ + p * 4);                                 \
}

#define AWRITEM(buf_) {                                                        \
    union { short s[16]; bf16x8 v[2]; } u_;                                    \
    _Pragma("unroll") for (int p = 0; p < 4; ++p) {                            \
        u_.s[p * 4 + 0] = f2bf(__expf(rAf[p].x - mr) * rr);                    \
        u_.s[p * 4 + 1] = f2bf(__expf(rAf[p].y - mr) * rr);                    \
        u_.s[p * 4 + 2] = f2bf(__expf(rAf[p].z - mr) * rr);                    \
        u_.s[p * 4 + 3] = f2bf(__expf(rAf[p].w - mr) * rr);                    \
    }                                                                          \
    const int row_ = tid >> 1;                                                 \
    const int c0_ = (tid & 1) * 32;                                            \
    char* a_ = sm + AHOFF + (buf_) * 8192 + row_ * 64;                         \
    *(bf16x8*)(a_ + SWZ(row_, c0_))      = u_.v[0];                            \
    *(bf16x8*)(a_ + SWZ(row_, c0_ + 16)) = u_.v[1];                            \
}

#define COMPUTEM(buf_) {                                                       \
    const char* ah_ = sm + AHOFF + (buf_) * 8192;                              \
    const char* al_ = sm + ALOFF + (buf_) * 8192;                              \
    const char* bh_ = sm + BHOFF + (buf_) * 8192;                              \
    const char* bl_ = sm + BLOFF + (buf_) * 8192;                              \
    bf16x8 afh[4], afl[4];                                                     \
    _Pragma("unroll") for (int fm = 0; fm < 4; ++fm) {                         \
        const int r_ = wr + fm * 16 + fr;                                      \
        const int o_ = r_ * 64 + SWZ(r_, fh);                                  \
        afh[fm] = *(const bf16x8*)(ah_ + o_);                                  \
        if constexpr (PAIR) afl[fm] = *(const bf16x8*)(al_ + o_);              \
    }                                                                          \
    _Pragma("unroll") for (int fn = 0; fn < 4; ++fn) {                         \
        const int r_ = wc + fn * 16 + fr;                                      \
        const int o_ = r_ * 64 + SWZ(r_, fh);                                  \
        bf16x8 bfh = *(const bf16x8*)(bh_ + o_);                               \
        _Pragma("unroll") for (int fm = 0; fm < 4; ++fm)                       \
            acc[fm][fn] = __builtin_amdgcn_mfma_f32_16x16x32_bf16(             \
                afh[fm], bfh, acc[fm][fn], 0, 0, 0);                           \
        if constexpr (PAIR) {                                                  \
            bf16x8 bfl = *(const bf16x8*)(bl_ + o_);                           \
            _Pragma("unroll") for (int fm = 0; fm < 4; ++fm) {                 \
                acc[fm][fn] = __builtin_amdgcn_mfma_f32_16x16x32_bf16(         \
                    afh[fm], bfl, acc[fm][fn], 0, 0, 0);                       \
                acc[fm][fn] = __builtin_amdgcn_mfma_f32_16x16x32_bf16(         \
                    afl[fm], bfh, acc[fm][fn], 0, 0, 0);                       \
            }                                                                  \
        }                                                                      \
    }                                                                          \
}

template<bool PAIR, bool AEXP, int EPI, int BIAS, bool STATS, bool QK>
__global__ __launch_bounds__(256, 2) void mgemm(
    const __hip_bfloat16* __restrict__ Ah, const __hip_bfloat16* __restrict__ Al,
    long long aB, int lda,
    const float* __restrict__ Af, long long afB,
    const __hip_bfloat16* __restrict__ Bh, const __hip_bfloat16* __restrict__ Bl,
    const __hip_bfloat16* __restrict__ Bh2, const __hip_bfloat16* __restrict__ Bl2,
    long long bB, int ldb,
    float* __restrict__ Of,
    __hip_bfloat16* __restrict__ Oh, __hip_bfloat16* __restrict__ Ol,
    __hip_bfloat16* __restrict__ Oh2, __hip_bfloat16* __restrict__ Ol2,
    long long oB, int ldo,
    const float* __restrict__ bias, const float* __restrict__ bias2,
    const float* __restrict__ resid, long long rB,
    const float* __restrict__ mrow, const float* __restrict__ rlrow,
    float* __restrict__ pmax, float* __restrict__ psum,
    int bbase, int zmask, int zshift,
    int kstep, int klen, float scale)
{
    constexpr int BHOFF = PAIR ? 32768 : 16384;
    constexpr int BLOFF = 49152;
    constexpr int LDSB = PAIR ? 65536 : 32768;
    __shared__ char sm[LDSB];

    const int tid = threadIdx.x;
    const int nx = gridDim.x;
    const int nwg = nx * gridDim.y;
    int id = blockIdx.y * nx + blockIdx.x;
    id = (id & 7) * (nwg >> 3) + (id >> 3);       // XCD swizzle (nwg % 8 == 0)
    const int n0 = (id % nx) * 128;
    const int m0 = (id / nx) * 128;
    const int z = blockIdx.z;
    const int bb = bbase + (z & zmask);
    const int sel = z >> zshift;
    const int kbeg = sel * kstep;

    const __hip_bfloat16* pAh = Ah + (long long)bb * aB;
    const __hip_bfloat16* pAl = Al;
    const __hip_bfloat16* pBh = ((QK && sel) ? Bh2 : Bh) + (long long)bb * bB;
    const __hip_bfloat16* pBl = Bl;
    if constexpr (PAIR) {
        pAl = Al + (long long)bb * aB;
        pBl = ((QK && sel) ? Bl2 : Bl) + (long long)bb * bB;
    }
    const float* pAf = Af;
    if constexpr (AEXP) pAf = Af + (long long)bb * afB;

    float mr = 0.f, rr = 0.f;
    if constexpr (AEXP) {
        const long long row = m0 + (tid >> 1);
        mr = mrow[(long long)bb * NPIX + row];
        rr = rlrow[(long long)bb * NPIX + row];
    }

    f32x4 acc[4][4];
#pragma unroll
    for (int i = 0; i < 4; ++i)
#pragma unroll
        for (int j = 0; j < 4; ++j) acc[i][j] = (f32x4){0.f, 0.f, 0.f, 0.f};

    const int lane = tid & 63, wid = tid >> 6;
    const int wr = (wid >> 1) * 64, wc = (wid & 1) * 64;
    const int fr = lane & 15, fh = (lane >> 4) * 16;
    const int nt = klen >> 5;

    float4 rAf[4];
    if constexpr (AEXP) { ALOADM(kbeg); }
    STAGE_AB(0, kbeg);
    if constexpr (AEXP) { AWRITEM(0); }
    asm volatile("s_waitcnt vmcnt(0)" ::: "memory");
    __syncthreads();

    for (int t = 0; t < nt; ++t) {
        const int cur = t & 1, nxt = (t + 1) & 1;
        if (t + 1 < nt) {
            if constexpr (AEXP) { ALOADM(kbeg + (t + 1) * 32); }
            STAGE_AB(nxt, kbeg + (t + 1) * 32);
        }
        COMPUTEM(cur);
        if constexpr (AEXP) { if (t + 1 < nt) AWRITEM(nxt); }
        asm volatile("s_waitcnt vmcnt(0)" ::: "memory");
        __syncthreads();
    }

    // fused softmax partial stats over this block's tile (per 64-col wave tile)
    if constexpr (STATS) {
#pragma unroll
        for (int fm = 0; fm < 4; ++fm)
#pragma unroll
        for (int j = 0; j < 4; ++j) {
            float v0 = acc[fm][0][j] * scale, v1 = acc[fm][1][j] * scale;
            float v2 = acc[fm][2][j] * scale, v3 = acc[fm][3][j] * scale;
            float rm = fmaxf(fmaxf(v0, v1), fmaxf(v2, v3));
#pragma unroll
            for (int off = 1; off < 16; off <<= 1)
                rm = fmaxf(rm, __shfl_xor(rm, off, 64));
            float se = __expf(v0 - rm) + __expf(v1 - rm) +
                       __expf(v2 - rm) + __expf(v3 - rm);
#pragma unroll
            for (int off = 1; off < 16; off <<= 1)
                se += __shfl_xor(se, off, 64);
            if (fr == 0) {
                const long long row = m0 + wr + fm * 16 + (lane >> 4) * 4 + j;
                const long long o = ((long long)bb * NPIX + row) * 64 + ((n0 + wc) >> 6);
                pmax[o] = rm;
                psum[o] = se;
            }
        }
    }

    // epilogue
    float* obF = nullptr;
    if constexpr (EPI == 0 || EPI == 3) obF = Of + (long long)z * oB;
    if constexpr (EPI == 2) obF = Of + (long long)bb * oB;
    __hip_bfloat16 *obH = nullptr, *obL = nullptr;
    const float* biasP = bias;
    if constexpr (EPI == 1) {
        obH = ((QK && sel) ? Oh2 : Oh) + (long long)bb * oB;
        obL = ((QK && sel) ? Ol2 : Ol);
        if (obL) obL += (long long)bb * oB;
        if constexpr (QK) biasP = sel ? bias2 : bias;
    }
    const float* residP = nullptr;
    if constexpr (EPI == 2) residP = resid + (long long)bb * rB;

#pragma unroll
    for (int fm = 0; fm < 4; ++fm)
#pragma unroll
    for (int fn = 0; fn < 4; ++fn)
#pragma unroll
    for (int j = 0; j < 4; ++j) {
        const long long gr = m0 + wr + fm * 16 + (lane >> 4) * 4 + j;
        const long long gc = n0 + wc + fn * 16 + fr;
        const long long o = gr * (long long)ldo + gc;
        float vv = acc[fm][fn][j];
        if constexpr (EPI == 0) {
            obF[o] = vv * scale;
        } else if constexpr (EPI == 3) {
            obF[o] = vv;
        } else if constexpr (EPI == 1) {
            if constexpr (BIAS == 1) vv += biasP[gr];
            if constexpr (BIAS == 2) vv += biasP[gc];
            short h = f2bf(vv);
            ((short*)obH)[o] = h;
            if (obL) ((short*)obL)[o] = f2bf(vv - bf2f(h));
        } else {
            obF[o] = vv + biasP[gr] + residP[o];
        }
    }
}

// ---------------------------------------------------------------------------
// Merge per-64col softmax partials -> per-row m, 1/l.
// ---------------------------------------------------------------------------
__global__ __launch_bounds__(256) void stat_merge(
    const float* __restrict__ pmax, const float* __restrict__ psum,
    float* __restrict__ mrow, float* __restrict__ rlrow)
{
    const long long r = (long long)blockIdx.x * 256 + threadIdx.x;
    const float* pm = pmax + r * 64;
    const float* ps = psum + r * 64;
    float M = -3.4e38f;
#pragma unroll
    for (int t = 0; t < 64; t += 4) {
        float4 a = *(const float4*)(pm + t);
        M = fmaxf(M, fmaxf(fmaxf(a.x, a.y), fmaxf(a.z, a.w)));
    }
    float L = 0.f;
#pragma unroll
    for (int t = 0; t < 64; t += 4) {
        float4 a = *(const float4*)(pm + t);
        float4 s = *(const float4*)(ps + t);
        L += s.x * __expf(a.x - M) + s.y * __expf(a.y - M) +
             s.z * __expf(a.z - M) + s.w * __expf(a.w - M);
    }
    mrow[r]  = M;
    rlrow[r] = 1.0f / L;
}

// ---------------------------------------------------------------------------
// Sum 4 split-K slices -> aoT bf16 hi/lo.
// ---------------------------------------------------------------------------
__global__ __launch_bounds__(256) void pv_reduce(
    const float* __restrict__ P4, long long sStride,
    __hip_bfloat16* __restrict__ oh, __hip_bfloat16* __restrict__ ol)
{
    const long long i = ((long long)blockIdx.x * 256 + threadIdx.x) * 4;
    float4 a = *(const float4*)(P4 + i);
    float4 b = *(const float4*)(P4 + sStride + i);
    float4 c = *(const float4*)(P4 + 2 * sStride + i);
    float4 d = *(const float4*)(P4 + 3 * sStride + i);
    float r0 = a.x + b.x + c.x + d.x, r1 = a.y + b.y + c.y + d.y;
    float r2 = a.z + b.z + c.z + d.z, r3 = a.w + b.w + c.w + d.w;
    union { short s[4]; long long v; } H, L;
    H.s[0] = f2bf(r0); L.s[0] = f2bf(r0 - bf2f(H.s[0]));
    H.s[1] = f2bf(r1); L.s[1] = f2bf(r1 - bf2f(H.s[1]));
    H.s[2] = f2bf(r2); L.s[2] = f2bf(r2 - bf2f(H.s[2]));
    H.s[3] = f2bf(r3); L.s[3] = f2bf(r3 - bf2f(H.s[3]));
    *(long long*)((short*)oh + i) = H.v;
    *(long long*)((short*)ol + i) = L.v;
}

// ---------------------------------------------------------------------------
// Host launcher
// ---------------------------------------------------------------------------
extern "C" void kernel_launch(void* const* d_in, const int* in_sizes, int n_in,
                              void* d_out, int out_size, void* d_ws, size_t ws_size,
                              hipStream_t stream)
{
    const float* x  = (const float*)d_in[0];
    const float* gs = (const float*)d_in[1];
    const float* gb = (const float*)d_in[2];
    const float* qw = (const float*)d_in[3];
    const float* qb = (const float*)d_in[4];
    const float* kw = (const float*)d_in[5];
    const float* kb = (const float*)d_in[6];
    const float* vw = (const float*)d_in[7];
    const float* vb = (const float*)d_in[8];
    const float* pw = (const float*)d_in[9];
    const float* pb = (const float*)d_in[10];
    float* out = (float*)d_out;

    char* w = (char*)d_ws;
    size_t used = 0;
    auto alloc = [&](size_t bytes) {
        char* p = w + used;
        used += (bytes + 255) & ~(size_t)255;
        return p;
    };
    const long long NC = (long long)NPIX * CH;      // 1M
    const long long SB = (long long)NPIX * NPIX;    // 16M

    __hip_bfloat16* hnT_h = (__hip_bfloat16*)alloc(BATCH * NC * 2);
    __hip_bfloat16* hnT_l = (__hip_bfloat16*)alloc(BATCH * NC * 2);
    __hip_bfloat16* qT_h  = (__hip_bfloat16*)alloc(BATCH * NC * 2);
    __hip_bfloat16* qT_l  = (__hip_bfloat16*)alloc(BATCH * NC * 2);
    __hip_bfloat16* kT_h  = (__hip_bfloat16*)alloc(BATCH * NC * 2);
    __hip_bfloat16* kT_l  = (__hip_bfloat16*)alloc(BATCH * NC * 2);
    __hip_bfloat16* v_h   = (__hip_bfloat16*)alloc(BATCH * NC * 2);
    __hip_bfloat16* aoT_h = (__hip_bfloat16*)alloc(BATCH * NC * 2);
    __hip_bfloat16* aoT_l = (__hip_bfloat16*)alloc(BATCH * NC * 2);
    __hip_bfloat16* w4h   = (__hip_bfloat16*)alloc(4 * 65536 * 2);
    __hip_bfloat16* w4l   = (__hip_bfloat16*)alloc(4 * 65536 * 2);
    float* meanb = (float*)alloc(BATCH * NGROUP * 4);
    float* rstdb = (float*)alloc(BATCH * NGROUP * 4);
    float* mrow  = (float*)alloc((size_t)BATCH * NPIX * 4);
    float* rlrow = (float*)alloc((size_t)BATCH * NPIX * 4);
    float* pmax  = (float*)alloc((size_t)BATCH * NPIX * 64 * 4);
    float* psum  = (float*)alloc((size_t)BATCH * NPIX * 64 * 4);

    const size_t tail_batched = (size_t)BATCH * SB * 4 + (size_t)16 * NC * 4;
    const bool batched = ws_size >= used + tail_batched;
    float* S  = (float*)alloc(batched ? (size_t)BATCH * SB * 4 : (size_t)SB * 4);
    float* P4 = (float*)alloc(batched ? (size_t)16 * NC * 4 : (size_t)4 * NC * 4);

    const __hip_bfloat16 *wq_h = w4h,          *wq_l = w4l;
    const __hip_bfloat16 *wk_h = w4h + 65536,  *wk_l = w4l + 65536;
    const __hip_bfloat16 *wv_h = w4h + 131072, *wv_l = w4l + 131072;
    const __hip_bfloat16 *wp_h = w4h + 196608, *wp_l = w4l + 196608;

    gn_stats<<<BATCH * NGROUP, 256, 0, stream>>>(x, meanb, rstdb);
    tn_cvt<<<dim3(NPIX / 64, CH / 64, BATCH), 256, 0, stream>>>(
        x, gs, gb, meanb, rstdb, hnT_h, hnT_l);
    wcvt<<<256, 256, 0, stream>>>(qw, kw, vw, pw, w4h, w4l);

    // q & k fused: qT/kT[i][c] (M=NPIX, N=CH, bias per col)
    mgemm<true, false, 1, 2, false, true><<<dim3(2, 32, 8), 256, 0, stream>>>(
        hnT_h, hnT_l, NC, CH,
        nullptr, 0,
        wq_h, wq_l, wk_h, wk_l, 0, CH,
        nullptr,
        qT_h, qT_l, kT_h, kT_l, NC, CH,
        qb, kb,
        nullptr, 0,
        nullptr, nullptr,
        nullptr, nullptr,
        0, 3, 2,
        0, CH, 1.0f);
    // v[c][j] (M=CH, N=NPIX, bias per row), hi only
    mgemm<true, false, 1, 1, false, false><<<dim3(32, 2, 4), 256, 0, stream>>>(
        wv_h, wv_l, 0, CH,
        nullptr, 0,
        hnT_h, hnT_l, nullptr, nullptr, NC, CH,
        nullptr,
        v_h, nullptr, nullptr, nullptr, NC, NPIX,
        vb, nullptr,
        nullptr, 0,
        nullptr, nullptr,
        nullptr, nullptr,
        0, 3, 2,
        0, CH, 1.0f);

    if (batched) {
        // S[i][j] + fused stats
        mgemm<true, false, 0, 0, true, false><<<dim3(32, 32, 4), 256, 0, stream>>>(
            qT_h, qT_l, NC, CH,
            nullptr, 0,
            kT_h, kT_l, nullptr, nullptr, NC, CH,
            S,
            nullptr, nullptr, nullptr, nullptr, SB, NPIX,
            nullptr, nullptr,
            nullptr, 0,
            nullptr, nullptr,
            pmax, psum,
            0, 3, 2,
            0, CH, ATTN_SCALE);
        stat_merge<<<BATCH * NPIX / 256, 256, 0, stream>>>(pmax, psum, mrow, rlrow);
        // PV split-K x4 -> fp32 partials
        mgemm<false, true, 3, 0, false, false><<<dim3(2, 32, 16), 256, 0, stream>>>(
            nullptr, nullptr, 0, NPIX,
            S, SB,
            v_h, nullptr, nullptr, nullptr, NC, NPIX,
            P4,
            nullptr, nullptr, nullptr, nullptr, NC, CH,
            nullptr, nullptr,
            nullptr, 0,
            mrow, rlrow,
            nullptr, nullptr,
            0, 3, 2,
            1024, 1024, 1.0f);
        pv_reduce<<<(int)(BATCH * NC / 4 / 256), 256, 0, stream>>>(
            P4, 4 * NC, aoT_h, aoT_l);
    } else {
        for (int b = 0; b < BATCH; ++b) {
            mgemm<true, false, 0, 0, true, false><<<dim3(32, 32, 1), 256, 0, stream>>>(
                qT_h, qT_l, NC, CH,
                nullptr, 0,
                kT_h, kT_l, nullptr, nullptr, NC, CH,
                S,
                nullptr, nullptr, nullptr, nullptr, 0, NPIX,
                nullptr, nullptr,
                nullptr, 0,
                nullptr, nullptr,
                pmax, psum,
                b, 0, 0,
                0, CH, ATTN_SCALE);
            stat_merge<<<NPIX / 256, 256, 0, stream>>>(
                pmax + (long long)b * NPIX * 64, psum + (long long)b * NPIX * 64,
                mrow + (long long)b * NPIX, rlrow + (long long)b * NPIX);
            mgemm<false, true, 3, 0, false, false><<<dim3(2, 32, 4), 256, 0, stream>>>(
                nullptr, nullptr, 0, NPIX,
                S, 0,
                v_h, nullptr, nullptr, nullptr, NC, NPIX,
                P4,
                nullptr, nullptr, nullptr, nullptr, NC, CH,
                nullptr, nullptr,
                nullptr, 0,
                mrow, rlrow,
                nullptr, nullptr,
                b, 0, 0,
                1024, 1024, 1.0f);
            pv_reduce<<<(int)(NC / 4 / 256), 256, 0, stream>>>(
                P4, NC, aoT_h + (long long)b * NC, aoT_l + (long long)b * NC);
        }
    }

    // out[c][n] = x + pb[c] + proj
    mgemm<true, false, 2, 1, false, false><<<dim3(32, 2, 4), 256, 0, stream>>>(
        wp_h, wp_l, 0, CH,
        nullptr, 0,
        aoT_h, aoT_l, nullptr, nullptr, NC, CH,
        out,
        nullptr, nullptr, nullptr, nullptr, NC, NPIX,
        pb, nullptr,
        x, NC,
        nullptr, nullptr,
        nullptr, nullptr,
        0, 3, 2,
        0, CH, 1.0f);
}

// Round 4
// 370.834 us; speedup vs baseline: 7.6830x; 1.3923x over previous
//
#include <hip/hip_runtime.h>
#include <hip/hip_bf16.h>

typedef __attribute__((ext_vector_type(8))) short bf16x8;
typedef __attribute__((ext_vector_type(4))) float f32x4;
static_assert(sizeof(bf16x8) == 16, "");

constexpr int BATCH = 4, CH = 256, NPIX = 4096, NGROUP = 32, CPG = 8;
constexpr float ATTN_SCALE = 0.0625f;  // C^-0.5
constexpr float GN_EPS = 1e-6f;

__device__ inline short f2bf(float v) {
    union { __hip_bfloat16 b; short s; } u;
    u.b = __float2bfloat16(v);
    return u.s;
}
__device__ inline float bf2f(short s) {
    union { __hip_bfloat16 b; short sv; } u;
    u.sv = s;
    return __bfloat162float(u.b);
}

// ---- async global->LDS (16B per lane), with reg-staged fallback ----------
#if defined(__has_builtin)
#if __has_builtin(__builtin_amdgcn_global_load_lds)
#define HAVE_GLDS 1
#endif
#endif

typedef const __attribute__((address_space(1))) char* gas_t;
typedef __attribute__((address_space(3))) char* las_t;

__device__ inline void gload16(const void* g, char* l) {
#ifdef HAVE_GLDS
    __builtin_amdgcn_global_load_lds((gas_t)g, (las_t)l, 16, 0, 0);
#else
    *(bf16x8*)l = *(const bf16x8*)g;
#endif
}

// LDS bank swizzle: byte-col (16B granular) XOR'd by row bits -> 2-way max.
#define SWZ(r_, c_) ((c_) ^ ((((r_) >> 1) & 3) << 4))

// Stage one 128x32 bf16 tile (8 KB) into LDS, pre-swizzled source (rule #21).
__device__ inline void stage_tile(const __hip_bfloat16* __restrict__ g,
                                  long long ld, long long row0, int k0,
                                  char* lds) {
#pragma unroll
    for (int i = 0; i < 2; ++i) {
        const int o = (int)threadIdx.x * 16 + i * 4096;
        const int row = o >> 6, col = o & 63;
        gload16((const char*)(g + (row0 + row) * ld + k0) + SWZ(row, col), lds + o);
    }
}

#define MFMA16(a_, b_, c_) __builtin_amdgcn_mfma_f32_16x16x32_bf16(a_, b_, c_, 0, 0, 0)

// ---------------------------------------------------------------------------
// K1: GroupNorm stats per (b, g): mean, rstd.
// ---------------------------------------------------------------------------
__global__ __launch_bounds__(256) void gn_stats(
    const float* __restrict__ x, float* __restrict__ meanb, float* __restrict__ rstdb)
{
    const int b = blockIdx.x >> 5;
    const int g = blockIdx.x & 31;
    const long long base = ((long long)b * CH + (long long)g * CPG) * NPIX;
    const float4* xp = (const float4*)(x + base);
    constexpr int NV = CPG * NPIX / 4;

    float s = 0.f, s2 = 0.f;
    for (int i = threadIdx.x; i < NV; i += 256) {
        float4 v = xp[i];
        s  += v.x + v.y + v.z + v.w;
        s2 += v.x * v.x + v.y * v.y + v.z * v.z + v.w * v.w;
    }
#pragma unroll
    for (int off = 32; off > 0; off >>= 1) {
        s  += __shfl_down(s,  off, 64);
        s2 += __shfl_down(s2, off, 64);
    }
    __shared__ float rs[4], rs2[4];
    const int wid = threadIdx.x >> 6, lane = threadIdx.x & 63;
    if (lane == 0) { rs[wid] = s; rs2[wid] = s2; }
    __syncthreads();
    if (threadIdx.x == 0) {
        float ts  = rs[0] + rs[1] + rs[2] + rs[3];
        float ts2 = rs2[0] + rs2[1] + rs2[2] + rs2[3];
        float inv = 1.0f / (float)(CPG * NPIX);
        float mu  = ts * inv;
        float var = ts2 * inv - mu * mu;
        meanb[blockIdx.x] = mu;
        rstdb[blockIdx.x] = rsqrtf(var + GN_EPS);
    }
}

// ---------------------------------------------------------------------------
// K2: transpose + normalize + convert: x[b][c][n] -> hnT_hi/lo[b][n][c] bf16.
// ---------------------------------------------------------------------------
__global__ __launch_bounds__(256) void tn_cvt(
    const float* __restrict__ x, const float* __restrict__ gs, const float* __restrict__ gb,
    const float* __restrict__ meanb, const float* __restrict__ rstdb,
    __hip_bfloat16* __restrict__ th, __hip_bfloat16* __restrict__ tl)
{
    __shared__ float t[64][65];
    const int b = blockIdx.z, c0 = blockIdx.y * 64, n0 = blockIdx.x * 64;
    const int tid = threadIdx.x;
    const int rr_ = tid >> 2, q4 = (tid & 3) * 16;
    {
        const int c = c0 + rr_;
        const int g = c >> 3;
        const float mu = meanb[b * NGROUP + g], rs = rstdb[b * NGROUP + g];
        const float A = gs[c] * rs, Bc = gb[c] - mu * A;
        const float* xs = x + ((long long)b * CH + c) * NPIX + n0 + q4;
#pragma unroll
        for (int p = 0; p < 4; ++p) {
            float4 vv = *(const float4*)(xs + p * 4);
            t[rr_][q4 + p * 4 + 0] = vv.x * A + Bc;
            t[rr_][q4 + p * 4 + 1] = vv.y * A + Bc;
            t[rr_][q4 + p * 4 + 2] = vv.z * A + Bc;
            t[rr_][q4 + p * 4 + 3] = vv.w * A + Bc;
        }
    }
    __syncthreads();
    {
        const int n = n0 + rr_;
        const long long ob = ((long long)b * NPIX + n) * CH + c0 + q4;
        union { short s[16]; bf16x8 v[2]; } hs, ls;
#pragma unroll
        for (int p = 0; p < 16; ++p) {
            float v = t[q4 + p][rr_];
            short h = f2bf(v);
            hs.s[p] = h;
            ls.s[p] = f2bf(v - bf2f(h));
        }
        *(bf16x8*)(th + ob)      = hs.v[0];
        *(bf16x8*)(th + ob + 8)  = hs.v[1];
        *(bf16x8*)(tl + ob)      = ls.v[0];
        *(bf16x8*)(tl + ob + 8)  = ls.v[1];
    }
}

// ---------------------------------------------------------------------------
// K3: convert the four 256x256 weight matrices to bf16 hi/lo (packed).
// ---------------------------------------------------------------------------
__global__ __launch_bounds__(256) void wcvt(
    const float* __restrict__ qw, const float* __restrict__ kw,
    const float* __restrict__ vw, const float* __restrict__ pw,
    __hip_bfloat16* __restrict__ wh, __hip_bfloat16* __restrict__ wl)
{
    const int idx = (blockIdx.x * 256 + threadIdx.x) * 4;
    const int which = idx >> 16;
    const float* src = which == 0 ? qw : which == 1 ? kw : which == 2 ? vw : pw;
    float4 vv = *(const float4*)(src + (idx & 65535));
    float a[4] = {vv.x, vv.y, vv.z, vv.w};
#pragma unroll
    for (int e = 0; e < 4; ++e) {
        short h = f2bf(a[e]);
        ((short*)wh)[idx + e] = h;
        ((short*)wl)[idx + e] = f2bf(a[e] - bf2f(h));
    }
}

// ---------------------------------------------------------------------------
// MFMA GEMM (as round 3, minus AEXP/STATS usage), EPI1 gains output scale.
// Out[m][n] = sum_k A[m][k]*B[n][k] (both K-contiguous).
// ---------------------------------------------------------------------------
constexpr int AHOFF = 0, ALOFF = 16384;

#define STAGE_AB(buf_, k0_) {                                                  \
    stage_tile(pAh, lda, m0, (k0_), sm + AHOFF + (buf_) * 8192);               \
    if constexpr (PAIR)                                                        \
        stage_tile(pAl, lda, m0, (k0_), sm + ALOFF + (buf_) * 8192);           \
    stage_tile(pBh, ldb, n0, (k0_), sm + BHOFF + (buf_) * 8192);               \
    if constexpr (PAIR)                                                        \
        stage_tile(pBl, ldb, n0, (k0_), sm + BLOFF + (buf_) * 8192);           \
}

#define COMPUTEM(buf_) {                                                       \
    const char* ah_ = sm + AHOFF + (buf_) * 8192;                              \
    const char* al_ = sm + ALOFF + (buf_) * 8192;                              \
    const char* bh_ = sm + BHOFF + (buf_) * 8192;                              \
    const char* bl_ = sm + BLOFF + (buf_) * 8192;                              \
    bf16x8 afh[4], afl[4];                                                     \
    _Pragma("unroll") for (int fm = 0; fm < 4; ++fm) {                         \
        const int r_ = wr + fm * 16 + fr;                                      \
        const int o_ = r_ * 64 + SWZ(r_, fh);                                  \
        afh[fm] = *(const bf16x8*)(ah_ + o_);                                  \
        if constexpr (PAIR) afl[fm] = *(const bf16x8*)(al_ + o_);              \
    }                                                                          \
    _Pragma("unroll") for (int fn = 0; fn < 4; ++fn) {                         \
        const int r_ = wc + fn * 16 + fr;                                      \
        const int o_ = r_ * 64 + SWZ(r_, fh);                                  \
        bf16x8 bfh = *(const bf16x8*)(bh_ + o_);                               \
        _Pragma("unroll") for (int fm = 0; fm < 4; ++fm)                       \
            acc[fm][fn] = MFMA16(afh[fm], bfh, acc[fm][fn]);                   \
        if constexpr (PAIR) {                                                  \
            bf16x8 bfl = *(const bf16x8*)(bl_ + o_);                           \
            _Pragma("unroll") for (int fm = 0; fm < 4; ++fm) {                 \
                acc[fm][fn] = MFMA16(afh[fm], bfl, acc[fm][fn]);               \
                acc[fm][fn] = MFMA16(afl[fm], bfh, acc[fm][fn]);               \
            }                                                                  \
        }                                                                      \
    }                                                                          \
}

template<bool PAIR, int EPI, int BIAS, bool QK>
__global__ __launch_bounds__(256, 2) void mgemm(
    const __hip_bfloat16* __restrict__ Ah, const __hip_bfloat16* __restrict__ Al,
    long long aB, int lda,
    const __hip_bfloat16* __restrict__ Bh, const __hip_bfloat16* __restrict__ Bl,
    const __hip_bfloat16* __restrict__ Bh2, const __hip_bfloat16* __restrict__ Bl2,
    long long bB, int ldb,
    float* __restrict__ Of,
    __hip_bfloat16* __restrict__ Oh, __hip_bfloat16* __restrict__ Ol,
    __hip_bfloat16* __restrict__ Oh2, __hip_bfloat16* __restrict__ Ol2,
    long long oB, int ldo,
    const float* __restrict__ bias, const float* __restrict__ bias2,
    const float* __restrict__ resid, long long rB,
    int zmask, int zshift,
    int Kd, float scale, float scale2)
{
    constexpr int BHOFF = PAIR ? 32768 : 16384;
    constexpr int BLOFF = 49152;
    constexpr int LDSB = PAIR ? 65536 : 32768;
    __shared__ __align__(16) char sm[LDSB];

    const int tid = threadIdx.x;
    const int nx = gridDim.x;
    const int nwg = nx * gridDim.y;
    int id = blockIdx.y * nx + blockIdx.x;
    id = (id & 7) * (nwg >> 3) + (id >> 3);       // XCD swizzle (nwg % 8 == 0)
    const int n0 = (id % nx) * 128;
    const int m0 = (id / nx) * 128;
    const int z = blockIdx.z;
    const int bb = z & zmask;
    const int sel = z >> zshift;

    const __hip_bfloat16* pAh = Ah + (long long)bb * aB;
    const __hip_bfloat16* pAl = Al;
    const __hip_bfloat16* pBh = ((QK && sel) ? Bh2 : Bh) + (long long)bb * bB;
    const __hip_bfloat16* pBl = Bl;
    if constexpr (PAIR) {
        pAl = Al + (long long)bb * aB;
        pBl = ((QK && sel) ? Bl2 : Bl) + (long long)bb * bB;
    }

    f32x4 acc[4][4];
#pragma unroll
    for (int i = 0; i < 4; ++i)
#pragma unroll
        for (int j = 0; j < 4; ++j) acc[i][j] = (f32x4){0.f, 0.f, 0.f, 0.f};

    const int lane = tid & 63, wid = tid >> 6;
    const int wr = (wid >> 1) * 64, wc = (wid & 1) * 64;
    const int fr = lane & 15, fh = (lane >> 4) * 16;
    const int nt = Kd >> 5;

    STAGE_AB(0, 0);
    asm volatile("s_waitcnt vmcnt(0)" ::: "memory");
    __syncthreads();

    for (int t = 0; t < nt; ++t) {
        const int cur = t & 1, nxt = (t + 1) & 1;
        if (t + 1 < nt) STAGE_AB(nxt, (t + 1) * 32);
        COMPUTEM(cur);
        asm volatile("s_waitcnt vmcnt(0)" ::: "memory");
        __syncthreads();
    }

    // epilogue
    float* obF = nullptr;
    if constexpr (EPI == 2) obF = Of + (long long)bb * oB;
    __hip_bfloat16 *obH = nullptr, *obL = nullptr;
    const float* biasP = bias;
    if constexpr (EPI == 1) {
        obH = ((QK && sel) ? Oh2 : Oh) + (long long)bb * oB;
        obL = ((QK && sel) ? Ol2 : Ol);
        if (obL) obL += (long long)bb * oB;
        if constexpr (QK) biasP = sel ? bias2 : bias;
    }
    const float* residP = nullptr;
    if constexpr (EPI == 2) residP = resid + (long long)bb * rB;
    const float osc = (QK && sel) ? scale2 : scale;

#pragma unroll
    for (int fm = 0; fm < 4; ++fm)
#pragma unroll
    for (int fn = 0; fn < 4; ++fn)
#pragma unroll
    for (int j = 0; j < 4; ++j) {
        const long long gr = m0 + wr + fm * 16 + (lane >> 4) * 4 + j;
        const long long gc = n0 + wc + fn * 16 + fr;
        const long long o = gr * (long long)ldo + gc;
        float vv = acc[fm][fn][j];
        if constexpr (EPI == 1) {
            if constexpr (BIAS == 1) vv += biasP[gr];
            if constexpr (BIAS == 2) vv += biasP[gc];
            vv *= osc;
            short h = f2bf(vv);
            ((short*)obH)[o] = h;
            if (obL) ((short*)obL)[o] = f2bf(vv - bf2f(h));
        } else {
            obF[o] = vv + biasP[gr] + residP[o];
        }
    }
}

// ---------------------------------------------------------------------------
// Fused flash attention (swapped QK^T, online softmax, defer-max).
// Block: 64 q-rows (4 waves x 16), KV tile 32. LDS 48 KB (Kh/Kl/V swizzled).
// qT already carries ATTN_SCALE and bias; kT pair; v hi-only.
// Output: aoT[i][c] bf16 hi/lo.
// ---------------------------------------------------------------------------
__global__ __launch_bounds__(256, 1) void flash_attn(
    const __hip_bfloat16* __restrict__ qh_g, const __hip_bfloat16* __restrict__ ql_g,
    const __hip_bfloat16* __restrict__ kh_g, const __hip_bfloat16* __restrict__ kl_g,
    const __hip_bfloat16* __restrict__ v_g,
    __hip_bfloat16* __restrict__ oh_g, __hip_bfloat16* __restrict__ ol_g)
{
    __shared__ __align__(16) char sm[49152];
    char* KH = sm;
    char* KL = sm + 16384;
    char* VB = sm + 32768;

    const int tid = threadIdx.x;
    const int w = tid >> 6, lane = tid & 63;
    const int g = lane >> 4, li = lane & 15;
    const int z = blockIdx.y;
    const long long zNC = (long long)z * CH * NPIX;
    const int i_g = blockIdx.x * 64 + w * 16 + li;

    // Q fragments (B-operand: lane holds Q[i = li][c = kf*32 + g*8 .. +7])
    bf16x8 qh[8], ql[8];
    {
        const __hip_bfloat16* qrh = qh_g + zNC + (long long)i_g * CH;
        const __hip_bfloat16* qrl = ql_g + zNC + (long long)i_g * CH;
#pragma unroll
        for (int kf = 0; kf < 8; ++kf) {
            qh[kf] = *(const bf16x8*)(qrh + kf * 32 + g * 8);
            ql[kf] = *(const bf16x8*)(qrl + kf * 32 + g * 8);
        }
    }

    f32x4 o[16];
#pragma unroll
    for (int i = 0; i < 16; ++i) o[i] = (f32x4){0.f, 0.f, 0.f, 0.f};
    float m = -1e30f, l = 0.f;

    bf16x8 kst[8], vst[4];

    // reg-prestage (T14): K hi/lo + V tile for j-tile jt_
#define FLOADS(jt_) {                                                          \
    _Pragma("unroll") for (int p = 0; p < 4; ++p) {                            \
        const int o2 = p * 4096 + tid * 16;                                    \
        const int kb = o2 >> 11, jr = (o2 >> 6) & 31, cb = o2 & 63;            \
        const char* sk = (const char*)(kh_g + zNC +                            \
            (long long)((jt_) + jr) * CH + kb * 32) + cb;                      \
        const char* sl = (const char*)(kl_g + zNC +                            \
            (long long)((jt_) + jr) * CH + kb * 32) + cb;                      \
        kst[p]     = *(const bf16x8*)sk;                                       \
        kst[p + 4] = *(const bf16x8*)sl;                                       \
        const char* sv = (const char*)(v_g + zNC +                             \
            (long long)(kb * 32 + jr) * NPIX + (jt_)) + cb;                    \
        vst[p] = *(const bf16x8*)sv;                                           \
    } }

#define FSTORES() {                                                            \
    _Pragma("unroll") for (int p = 0; p < 4; ++p) {                            \
        const int o2 = p * 4096 + tid * 16;                                    \
        const int kb = o2 >> 11, jr = (o2 >> 6) & 31, cb = o2 & 63;            \
        *(bf16x8*)(KH + kb * 2048 + jr * 64 + SWZ(jr, cb)) = kst[p];           \
        *(bf16x8*)(KL + kb * 2048 + jr * 64 + SWZ(jr, cb)) = kst[p + 4];       \
        *(bf16x8*)(VB + kb * 2048 + jr * 64 + SWZ(jr, cb)) = vst[p];           \
    } }

    FLOADS(0);
    FSTORES();
    __syncthreads();

    const int nt = NPIX / 32;
    for (int t = 0; t < nt; ++t) {
        if (t + 1 < nt) FLOADS((t + 1) * 32);

        // S^T[j][i] = K . Q  (3-pass split-bf16); lane: col i = li, rows j = fmj*16+4g+r
        f32x4 s0 = (f32x4){0.f, 0.f, 0.f, 0.f};
        f32x4 s1 = (f32x4){0.f, 0.f, 0.f, 0.f};
#pragma unroll
        for (int kf = 0; kf < 8; ++kf) {
            const int r0 = li, r1 = 16 + li;
            const int a0 = kf * 2048 + r0 * 64 + SWZ(r0, g * 16);
            const int a1 = kf * 2048 + r1 * 64 + SWZ(r1, g * 16);
            bf16x8 kh0 = *(const bf16x8*)(KH + a0);
            bf16x8 kh1 = *(const bf16x8*)(KH + a1);
            bf16x8 kl0 = *(const bf16x8*)(KL + a0);
            bf16x8 kl1 = *(const bf16x8*)(KL + a1);
            s0 = MFMA16(kh0, qh[kf], s0);
            s0 = MFMA16(kh0, ql[kf], s0);
            s0 = MFMA16(kl0, qh[kf], s0);
            s1 = MFMA16(kh1, qh[kf], s1);
            s1 = MFMA16(kh1, ql[kf], s1);
            s1 = MFMA16(kl1, qh[kf], s1);
        }

        // online softmax, per-lane row i = li
        float tm = fmaxf(fmaxf(fmaxf(s0[0], s0[1]), fmaxf(s0[2], s0[3])),
                         fmaxf(fmaxf(s1[0], s1[1]), fmaxf(s1[2], s1[3])));
        tm = fmaxf(tm, __shfl_xor(tm, 16, 64));
        tm = fmaxf(tm, __shfl_xor(tm, 32, 64));
        if (__any(tm > m + 8.0f)) {            // defer-max (T13)
            const float mn = fmaxf(m, tm);
            const float f = __expf(m - mn);
            m = mn; l *= f;
            const float fr0 = __shfl(f, 4 * g + 0, 64);
            const float fr1 = __shfl(f, 4 * g + 1, 64);
            const float fr2 = __shfl(f, 4 * g + 2, 64);
            const float fr3 = __shfl(f, 4 * g + 3, 64);
#pragma unroll
            for (int fn = 0; fn < 16; ++fn) {
                o[fn][0] *= fr0; o[fn][1] *= fr1;
                o[fn][2] *= fr2; o[fn][3] *= fr3;
            }
        }
        const float p0 = __expf(s0[0] - m), p1 = __expf(s0[1] - m);
        const float p2 = __expf(s0[2] - m), p3 = __expf(s0[3] - m);
        const float p4 = __expf(s1[0] - m), p5 = __expf(s1[1] - m);
        const float p6 = __expf(s1[2] - m), p7 = __expf(s1[3] - m);
        float ls = ((p0 + p1) + (p2 + p3)) + ((p4 + p5) + (p6 + p7));
        ls += __shfl_xor(ls, 16, 64);
        ls += __shfl_xor(ls, 32, 64);
        l += ls;

        // P -> bf16 A-fragment: lane needs P[i = li][j = 8g .. 8g+7]
        const unsigned int c0p = (unsigned int)(unsigned short)f2bf(p0) |
                                 ((unsigned int)(unsigned short)f2bf(p1) << 16);
        const unsigned int c1p = (unsigned int)(unsigned short)f2bf(p2) |
                                 ((unsigned int)(unsigned short)f2bf(p3) << 16);
        const unsigned int c2p = (unsigned int)(unsigned short)f2bf(p4) |
                                 ((unsigned int)(unsigned short)f2bf(p5) << 16);
        const unsigned int c3p = (unsigned int)(unsigned short)f2bf(p6) |
                                 ((unsigned int)(unsigned short)f2bf(p7) << 16);
        const int s0l = li + (((2 * g) & 3) << 4);
        const int s1l = li + (((2 * g + 1) & 3) << 4);
        const unsigned int a0h = __shfl(c0p, s0l, 64), a1h = __shfl(c1p, s0l, 64);
        const unsigned int a2h = __shfl(c0p, s1l, 64), a3h = __shfl(c1p, s1l, 64);
        const unsigned int a0l = __shfl(c2p, s0l, 64), a1l = __shfl(c3p, s0l, 64);
        const unsigned int a2l = __shfl(c2p, s1l, 64), a3l = __shfl(c3p, s1l, 64);
        union { unsigned int u[4]; bf16x8 v; } pau;
        const bool hi = g >= 2;
        pau.u[0] = hi ? a0l : a0h;
        pau.u[1] = hi ? a1l : a1h;
        pau.u[2] = hi ? a2l : a2h;
        pau.u[3] = hi ? a3l : a3h;

        // PV: O[i][ch] += P . V
#pragma unroll
        for (int fn = 0; fn < 16; ++fn) {
            const int chl = (fn & 1) * 16 + li;
            bf16x8 vf = *(const bf16x8*)(VB + (fn >> 1) * 2048 + chl * 64 +
                                         SWZ(chl, g * 16));
            o[fn] = MFMA16(pau.v, vf, o[fn]);
        }

        __syncthreads();
        if (t + 1 < nt) FSTORES();
        __syncthreads();
    }
#undef FLOADS
#undef FSTORES

    // epilogue: O /= l -> aoT hi/lo
    const float rl = 1.0f / l;
    const float r0 = __shfl(rl, 4 * g + 0, 64);
    const float r1 = __shfl(rl, 4 * g + 1, 64);
    const float r2 = __shfl(rl, 4 * g + 2, 64);
    const float r3 = __shfl(rl, 4 * g + 3, 64);
    const long long ib = (long long)blockIdx.x * 64 + w * 16 + 4 * g;
#pragma unroll
    for (int fn = 0; fn < 16; ++fn) {
        const int ch = fn * 16 + li;
        const float vv0 = o[fn][0] * r0, vv1 = o[fn][1] * r1;
        const float vv2 = o[fn][2] * r2, vv3 = o[fn][3] * r3;
        const float vvs[4] = {vv0, vv1, vv2, vv3};
#pragma unroll
        for (int r = 0; r < 4; ++r) {
            const long long off = zNC + (ib + r) * CH + ch;
            const short h = f2bf(vvs[r]);
            ((short*)oh_g)[off] = h;
            ((short*)ol_g)[off] = f2bf(vvs[r] - bf2f(h));
        }
    }
}

// ---------------------------------------------------------------------------
// Host launcher
// ---------------------------------------------------------------------------
extern "C" void kernel_launch(void* const* d_in, const int* in_sizes, int n_in,
                              void* d_out, int out_size, void* d_ws, size_t ws_size,
                              hipStream_t stream)
{
    const float* x  = (const float*)d_in[0];
    const float* gs = (const float*)d_in[1];
    const float* gb = (const float*)d_in[2];
    const float* qw = (const float*)d_in[3];
    const float* qb = (const float*)d_in[4];
    const float* kw = (const float*)d_in[5];
    const float* kb = (const float*)d_in[6];
    const float* vw = (const float*)d_in[7];
    const float* vb = (const float*)d_in[8];
    const float* pw = (const float*)d_in[9];
    const float* pb = (const float*)d_in[10];
    float* out = (float*)d_out;

    char* w = (char*)d_ws;
    size_t used = 0;
    auto alloc = [&](size_t bytes) {
        char* p = w + used;
        used += (bytes + 255) & ~(size_t)255;
        return p;
    };
    const long long NC = (long long)NPIX * CH;      // 1M

    __hip_bfloat16* hnT_h = (__hip_bfloat16*)alloc(BATCH * NC * 2);
    __hip_bfloat16* hnT_l = (__hip_bfloat16*)alloc(BATCH * NC * 2);
    __hip_bfloat16* qT_h  = (__hip_bfloat16*)alloc(BATCH * NC * 2);
    __hip_bfloat16* qT_l  = (__hip_bfloat16*)alloc(BATCH * NC * 2);
    __hip_bfloat16* kT_h  = (__hip_bfloat16*)alloc(BATCH * NC * 2);
    __hip_bfloat16* kT_l  = (__hip_bfloat16*)alloc(BATCH * NC * 2);
    __hip_bfloat16* v_h   = (__hip_bfloat16*)alloc(BATCH * NC * 2);
    __hip_bfloat16* aoT_h = (__hip_bfloat16*)alloc(BATCH * NC * 2);
    __hip_bfloat16* aoT_l = (__hip_bfloat16*)alloc(BATCH * NC * 2);
    __hip_bfloat16* w4h   = (__hip_bfloat16*)alloc(4 * 65536 * 2);
    __hip_bfloat16* w4l   = (__hip_bfloat16*)alloc(4 * 65536 * 2);
    float* meanb = (float*)alloc(BATCH * NGROUP * 4);
    float* rstdb = (float*)alloc(BATCH * NGROUP * 4);
    (void)ws_size;

    const __hip_bfloat16 *wq_h = w4h,          *wq_l = w4l;
    const __hip_bfloat16 *wk_h = w4h + 65536,  *wk_l = w4l + 65536;
    const __hip_bfloat16 *wv_h = w4h + 131072, *wv_l = w4l + 131072;
    const __hip_bfloat16 *wp_h = w4h + 196608, *wp_l = w4l + 196608;

    gn_stats<<<BATCH * NGROUP, 256, 0, stream>>>(x, meanb, rstdb);
    tn_cvt<<<dim3(NPIX / 64, CH / 64, BATCH), 256, 0, stream>>>(
        x, gs, gb, meanb, rstdb, hnT_h, hnT_l);
    wcvt<<<256, 256, 0, stream>>>(qw, kw, vw, pw, w4h, w4l);

    // q & k fused: qT/kT[i][c]; q gets ATTN_SCALE folded in (bias first).
    mgemm<true, 1, 2, true><<<dim3(2, 32, 8), 256, 0, stream>>>(
        hnT_h, hnT_l, NC, CH,
        wq_h, wq_l, wk_h, wk_l, 0, CH,
        nullptr,
        qT_h, qT_l, kT_h, kT_l, NC, CH,
        qb, kb,
        nullptr, 0,
        3, 2,
        CH, ATTN_SCALE, 1.0f);
    // v[c][j] (M=CH, N=NPIX, bias per row), hi only
    mgemm<true, 1, 1, false><<<dim3(32, 2, 4), 256, 0, stream>>>(
        wv_h, wv_l, 0, CH,
        hnT_h, hnT_l, nullptr, nullptr, NC, CH,
        nullptr,
        v_h, nullptr, nullptr, nullptr, NC, NPIX,
        vb, nullptr,
        nullptr, 0,
        3, 2,
        CH, 1.0f, 1.0f);

    // fused attention: aoT[i][c] hi/lo
    flash_attn<<<dim3(NPIX / 64, BATCH), 256, 0, stream>>>(
        qT_h, qT_l, kT_h, kT_l, v_h, aoT_h, aoT_l);

    // out[c][n] = x + pb[c] + proj
    mgemm<true, 2, 1, false><<<dim3(32, 2, 4), 256, 0, stream>>>(
        wp_h, wp_l, 0, CH,
        aoT_h, aoT_l, nullptr, nullptr, NC, CH,
        out,
        nullptr, nullptr, nullptr, nullptr, NC, NPIX,
        pb, nullptr,
        x, NC,
        3, 2,
        CH, 1.0f, 1.0f);
}